// Round 13
// baseline (323.007 us; speedup 1.0000x reference)
//
#include <hip/hip_runtime.h>
#include <math.h>

#define N_NODES 50000
#define N_EDGES 200000
#define N_GRAPHS 1024
#define DIM 24
#define EF 8
#define EH 128
#define DD 576   // 24*24
#define HSTR 136 // hs row stride in f16: 128 + 8 pad (breaks stage-A/read bank conflicts)

typedef __attribute__((ext_vector_type(8))) _Float16 f16x8;
typedef __attribute__((ext_vector_type(4))) _Float16 f16x4;
typedef __attribute__((ext_vector_type(2))) _Float16 f16x2;
typedef __attribute__((ext_vector_type(4))) float float4e;
typedef _Float16 f16;

// ---------- helpers ----------
static __device__ __forceinline__ float sigm(float x) { return 1.0f / (1.0f + expf(-x)); }

// ---------- prep: deg atomics + Bz swizzle + rootT in one dispatch ----------
// blocks 0..781: deg; 782..1169: Bz; 1170..1172: rootT.
// Bz layout: [p 97][nt 2][lane 64][kk 8] f16; lane = quad*16+l16,
// element = B[k32=quad*8+kk][n=nt*16+l16] (n>=24 -> 0). p = si*24+i covers
// k-window si*32..+32 of x-feature i; p=96 = bias block. 198,656 B, L2-resident.
__global__ __launch_bounds__(256) void prep_kernel(
    const int* __restrict__ dst, int* __restrict__ deg,
    const float* __restrict__ w2, const float* __restrict__ b2,
    const float* __restrict__ root,
    f16* __restrict__ Bz, float* __restrict__ rootT)
{
    const int b = blockIdx.x, t = threadIdx.x;
    if (b < 782) {
        int i = b * 256 + t;
        if (i < N_EDGES) atomicAdd(&deg[dst[i]], 1);
        return;
    }
    if (b < 1170) {
        int idx = (b - 782) * 256 + t;
        if (idx >= 97 * 2 * 64 * 8) return;
        int kk = idx & 7, lane = (idx >> 3) & 63, nt = (idx >> 9) & 1, p = idx >> 10;
        int q = lane >> 4, l16 = lane & 15, n = nt * 16 + l16;
        float v = 0.0f;
        if (p < 96) {
            int si = p / 24, i = p % 24;
            int k = si * 32 + q * 8 + kk;
            if (n < 24) v = w2[(size_t)k * DD + i * 24 + n];
        } else {
            int i2 = q * 8 + kk;
            if (i2 < 24 && n < 24) v = b2[i2 * 24 + n];
        }
        Bz[idx] = (f16)v;
        return;
    }
    int idx = (b - 1170) * 256 + t;   // rootT[o][i] = root[i][o]
    if (idx < DD) {
        int i = idx / 24, o = idx % 24;
        rootT[o * 24 + i] = root[idx];
    }
}

// ---------- fused NNConv: h-MLP + per-edge matvec as one z-GEMM, no W ----------
// Round-13 change: block 512 (8 waves, 256 edges), LDS 69.6KB -> 2 blocks/CU
// = SAME 16 waves/CU as the 256-thr/4-block config, but only 2 (not 4)
// independent Bz sweep-windows per CU. r12 arithmetic showed ~300cyc/step of
// exposed b-load latency = L2, because 4 drifting blocks x 24KB windows (96KB)
// thrash the 32KB L1. 2 windows (48KB, 8 barrier-locked waves each) mostly
// fit -> b-loads become L1-hits. Wave geometry (M=32, depth-4 prefetch, raw
// in-loop barriers) unchanged from the validated r12 form.
__global__ __launch_bounds__(512, 4) void conv_kernel(
    const float* __restrict__ x, const float* __restrict__ ea,
    const float* __restrict__ w1, const float* __restrict__ b1,
    const f16* __restrict__ Bz,
    const int* __restrict__ src, const int* __restrict__ dst,
    float* __restrict__ agg)
{
    __shared__ f16 hs[256 * HSTR];   // 69,632 B -> 2 blocks/CU (16 waves/CU)

    const int t  = threadIdx.x;
    const int e0 = blockIdx.x * 256;

    const int lane = t & 63;
    const int wave = t >> 6;             // 0..7: wave owns edges e0+wave*32 .. +32
    const int l16  = lane & 15;          // A row (edge) / B col / C col
    const int quad = lane >> 4;          // k sub-block / C row group
    const int ebase = e0 + wave * 32;

    // ---- x rows for both m-tiles -> f16 registers (issued first; L1 dedups) ----
    f16x2 xa[12], xb[12];
    {
        int ega = ebase + l16;      if (ega >= N_EDGES) ega = N_EDGES - 1;
        int egb = ebase + 16 + l16; if (egb >= N_EDGES) egb = N_EDGES - 1;
        const float* xra = x + (size_t)src[ega] * DIM;
        const float* xrb = x + (size_t)src[egb] * DIM;
        #pragma unroll
        for (int j4 = 0; j4 < 6; ++j4) {
            float4 va = *(const float4*)(xra + j4 * 4);
            float4 vb = *(const float4*)(xrb + j4 * 4);
            xa[j4 * 2]     = (f16x2){(f16)va.x, (f16)va.y};
            xa[j4 * 2 + 1] = (f16x2){(f16)va.z, (f16)va.w};
            xb[j4 * 2]     = (f16x2){(f16)vb.x, (f16)vb.y};
            xb[j4 * 2 + 1] = (f16x2){(f16)vb.z, (f16)vb.w};
        }
    }

    // ---- stage A: h = relu(ea@w1+b1) -> hs[edge][k]; thread = 4-k-slice x 16 edges ----
    {
        const int s5 = t & 31;           // k = s5*4 .. s5*4+3
        const int eb = (t >> 5) * 16;    // 16 groups x 16 edges = 256 edges
        float wv[EF][4];
        #pragma unroll
        for (int j = 0; j < EF; ++j) {
            float4 v = *(const float4*)(w1 + j * EH + s5 * 4);
            wv[j][0] = v.x; wv[j][1] = v.y; wv[j][2] = v.z; wv[j][3] = v.w;
        }
        float4 bv = *(const float4*)(b1 + s5 * 4);
        const float bvv[4] = {bv.x, bv.y, bv.z, bv.w};
        #pragma unroll
        for (int e = 0; e < 16; ++e) {
            int eg = e0 + eb + e; if (eg >= N_EDGES) eg = N_EDGES - 1;  // clamp tail
            const float* ear = ea + (size_t)eg * EF;
            float4 a0 = *(const float4*)ear;
            float4 a1 = *(const float4*)(ear + 4);
            const float av[EF] = {a0.x, a0.y, a0.z, a0.w, a1.x, a1.y, a1.z, a1.w};
            float r[4] = {bvv[0], bvv[1], bvv[2], bvv[3]};
            #pragma unroll
            for (int j = 0; j < EF; ++j)
                #pragma unroll
                for (int c = 0; c < 4; ++c)
                    r[c] = fmaf(av[j], wv[j][c], r[c]);
            f16x4 hq = { (f16)fmaxf(r[0], 0.0f), (f16)fmaxf(r[1], 0.0f),
                         (f16)fmaxf(r[2], 0.0f), (f16)fmaxf(r[3], 0.0f) };
            *(f16x4*)&hs[(eb + e) * HSTR + s5 * 4] = hq;
        }
    }

    // ---- prime depth-4 b-frag pipeline (independent of LDS; overlaps barrier) ----
    const f16x8* bz = (const f16x8*)Bz + lane;
    f16x8 pb0[4], pb1[4];
    #pragma unroll
    for (int s = 0; s < 4; ++s) { pb0[s] = bz[s * 128]; pb1[s] = bz[s * 128 + 64]; }

    __syncthreads();   // correctness: hs visible to all waves (full drain OK here)

    float4e a00 = {0.f,0.f,0.f,0.f}, a01 = {0.f,0.f,0.f,0.f};
    float4e a10 = {0.f,0.f,0.f,0.f}, a11 = {0.f,0.f,0.f,0.f};

    #pragma unroll
    for (int si = 0; si < 4; ++si) {
        union { f16x8 v; f16x2 p[4]; } h0u, h1u;
        h0u.v = *(const f16x8*)&hs[(wave * 32 + l16) * HSTR + si * 32 + quad * 8];
        h1u.v = *(const f16x8*)&hs[(wave * 32 + 16 + l16) * HSTR + si * 32 + quad * 8];
        #pragma unroll
        for (int i = 0; i < 24; ++i) {
            const int p = si * 24 + i;          // compile-time
            f16x8 b0 = pb0[p & 3], b1v = pb1[p & 3];
            if (p + 4 <= 96) {                  // prefetch 4 steps ahead into freed slot
                pb0[p & 3] = bz[(p + 4) * 128];
                pb1[p & 3] = bz[(p + 4) * 128 + 64];
            }
            f16 xea = (i & 1) ? xa[i >> 1][1] : xa[i >> 1][0];
            f16 xeb = (i & 1) ? xb[i >> 1][1] : xb[i >> 1][0];
            f16x2 xa2 = {xea, xea}, xb2 = {xeb, xeb};
            union { f16x8 v; f16x2 p[4]; } a0u, a1u;
            #pragma unroll
            for (int j = 0; j < 4; ++j) {
                a0u.p[j] = h0u.p[j] * xa2;      // v_pk_mul_f16
                a1u.p[j] = h1u.p[j] * xb2;
            }
            a00 = __builtin_amdgcn_mfma_f32_16x16x32_f16(a0u.v, b0,  a00, 0, 0, 0);
            a10 = __builtin_amdgcn_mfma_f32_16x16x32_f16(a1u.v, b0,  a10, 0, 0, 0);
            a01 = __builtin_amdgcn_mfma_f32_16x16x32_f16(a0u.v, b1v, a01, 0, 0, 0);
            a11 = __builtin_amdgcn_mfma_f32_16x16x32_f16(a1u.v, b1v, a11, 0, 0, 0);
            // lockstep hint only (no data dep): RAW barrier, no vmcnt drain.
            if ((p % 12) == 11) __builtin_amdgcn_s_barrier();
        }
    }

    // ---- bias step (p = 96): A = x row slices, B = b2 reshaped; frags in slot 0 ----
    {
        union { f16x8 v; f16x2 p[4]; } a0u, a1u;
        f16x2 z2 = {(f16)0.f, (f16)0.f};
        if (quad == 0)      { a0u.p[0]=xa[0]; a0u.p[1]=xa[1]; a0u.p[2]=xa[2];  a0u.p[3]=xa[3];
                              a1u.p[0]=xb[0]; a1u.p[1]=xb[1]; a1u.p[2]=xb[2];  a1u.p[3]=xb[3];  }
        else if (quad == 1) { a0u.p[0]=xa[4]; a0u.p[1]=xa[5]; a0u.p[2]=xa[6];  a0u.p[3]=xa[7];
                              a1u.p[0]=xb[4]; a1u.p[1]=xb[5]; a1u.p[2]=xb[6];  a1u.p[3]=xb[7];  }
        else if (quad == 2) { a0u.p[0]=xa[8]; a0u.p[1]=xa[9]; a0u.p[2]=xa[10]; a0u.p[3]=xa[11];
                              a1u.p[0]=xb[8]; a1u.p[1]=xb[9]; a1u.p[2]=xb[10]; a1u.p[3]=xb[11]; }
        else                { a0u.p[0]=z2; a0u.p[1]=z2; a0u.p[2]=z2; a0u.p[3]=z2;
                              a1u.p[0]=z2; a1u.p[1]=z2; a1u.p[2]=z2; a1u.p[3]=z2; }
        a00 = __builtin_amdgcn_mfma_f32_16x16x32_f16(a0u.v, pb0[0], a00, 0, 0, 0);
        a10 = __builtin_amdgcn_mfma_f32_16x16x32_f16(a1u.v, pb0[0], a10, 0, 0, 0);
        a01 = __builtin_amdgcn_mfma_f32_16x16x32_f16(a0u.v, pb1[0], a01, 0, 0, 0);
        a11 = __builtin_amdgcn_mfma_f32_16x16x32_f16(a1u.v, pb1[0], a11, 0, 0, 0);
    }

    // ---- scatter: C row = quad*4+r (edge), col = l16 (+16) = o ----
    #pragma unroll
    for (int r = 0; r < 4; ++r) {
        int er = ebase + quad * 4 + r;
        if (er < N_EDGES) {
            int d = dst[er];
            atomicAdd(&agg[(size_t)d * DIM + l16], a00[r]);
            if (l16 < 8) atomicAdd(&agg[(size_t)d * DIM + 16 + l16], a01[r]);
        }
        int er2 = ebase + 16 + quad * 4 + r;
        if (er2 < N_EDGES) {
            int d = dst[er2];
            atomicAdd(&agg[(size_t)d * DIM + l16], a10[r]);
            if (l16 < 8) atomicAdd(&agg[(size_t)d * DIM + 16 + l16], a11[r]);
        }
    }
}

// ---------- combine: x_out = [relu](agg/max(deg,1) + x_in@rootT^T + bias) ----------
// Vectorized: thread = (node, quarter of 6 outputs); float4 x/rootT loads.
// zero_agg=1: write agg=0 after reading (folds the inter-layer memset).
__global__ __launch_bounds__(256) void combine_kernel(
    const float* __restrict__ x_in, float* __restrict__ agg,
    const int* __restrict__ deg, const float* __restrict__ rootT,
    const float* __restrict__ bias, float* __restrict__ x_out,
    int do_relu, int zero_agg)
{
    int gid = blockIdx.x * 256 + threadIdx.x;
    int v = gid >> 2, q = gid & 3;
    if (v >= N_NODES) return;
    const int o0 = q * 6;

    float xv[24];
    const float4* xr = (const float4*)(x_in + (size_t)v * DIM);
    #pragma unroll
    for (int j = 0; j < 6; ++j) *(float4*)&xv[j * 4] = xr[j];

    int dg = deg[v];
    float dinv = 1.0f / (dg > 0 ? (float)dg : 1.0f);
    float* aggr = agg + (size_t)v * DIM + o0;

    float r[6];
    #pragma unroll
    for (int u = 0; u < 6; ++u) {
        int o = o0 + u;
        float a = aggr[u] * dinv + bias[o];
        const float4* rt = (const float4*)(rootT + o * 24);
        #pragma unroll
        for (int j = 0; j < 6; ++j) {
            float4 w = rt[j];
            a = fmaf(xv[j*4+0], w.x, a); a = fmaf(xv[j*4+1], w.y, a);
            a = fmaf(xv[j*4+2], w.z, a); a = fmaf(xv[j*4+3], w.w, a);
        }
        r[u] = do_relu ? fmaxf(a, 0.0f) : a;
    }
    if (zero_agg) {
        #pragma unroll
        for (int u = 0; u < 6; ++u) aggr[u] = 0.0f;
    }
    float* xo = x_out + (size_t)v * DIM + o0;
    #pragma unroll
    for (int u = 0; u < 6; ++u) xo[u] = r[u];
}

// ---------- fused Set2Set (3x LSTM+attention) + head: one block per graph ----------
__global__ __launch_bounds__(64) void s2s_kernel(
    const float* __restrict__ x, const int* __restrict__ batch,
    const float* __restrict__ w_ih, const float* __restrict__ w_hh,
    const float* __restrict__ b_ih, const float* __restrict__ b_hh,
    const float* __restrict__ w_fc2, const float* __restrict__ b_fc2,
    const float* __restrict__ w_fc3, const float* __restrict__ b_fc3,
    float* __restrict__ out)
{
    const int g = blockIdx.x;
    const int t = threadIdx.x;     // 64 = 1 wave
    __shared__ float qs[48];       // q_star = [q | r]
    __shared__ float hh[24], cc[24], gates[96], zl[8];
    __shared__ int s_lo, s_hi;

    if (t == 0) {
        int lo = 0, hi = N_NODES;
        while (lo < hi) { int m = (lo + hi) >> 1; if (batch[m] < g) lo = m + 1; else hi = m; }
        s_lo = lo;
        int lo2 = lo; hi = N_NODES;
        while (lo2 < hi) { int m = (lo2 + hi) >> 1; if (batch[m] <= g) lo2 = m + 1; else hi = m; }
        s_hi = lo2;
    }
    if (t < 48) qs[t] = 0.0f;
    if (t < 24) { hh[t] = 0.0f; cc[t] = 0.0f; }
    __syncthreads();
    const int lo = s_lo, hi = s_hi;

    for (int it = 0; it < 3; ++it) {
        // ---- LSTM gates (float4 weight loads) ----
        for (int rr = t; rr < 96; rr += 64) {
            float a = b_ih[rr] + b_hh[rr];
            const float* wi = w_ih + (size_t)rr * 48;
            const float* wh = w_hh + (size_t)rr * 24;
            #pragma unroll
            for (int j4 = 0; j4 < 12; ++j4) {
                float4 w = *(const float4*)(wi + j4 * 4);
                a = fmaf(qs[j4*4+0], w.x, a); a = fmaf(qs[j4*4+1], w.y, a);
                a = fmaf(qs[j4*4+2], w.z, a); a = fmaf(qs[j4*4+3], w.w, a);
            }
            #pragma unroll
            for (int j4 = 0; j4 < 6; ++j4) {
                float4 w = *(const float4*)(wh + j4 * 4);
                a = fmaf(hh[j4*4+0], w.x, a); a = fmaf(hh[j4*4+1], w.y, a);
                a = fmaf(hh[j4*4+2], w.z, a); a = fmaf(hh[j4*4+3], w.w, a);
            }
            gates[rr] = a;
        }
        __syncthreads();
        if (t < 24) {
            float c = sigm(gates[24 + t]) * cc[t] + sigm(gates[t]) * tanhf(gates[48 + t]);
            cc[t] = c;
            float h = sigm(gates[72 + t]) * tanhf(c);
            hh[t] = h;
            qs[t] = h;               // q part of q_star
        }
        __syncthreads();

        // ---- attention: single-pass online softmax over this graph's nodes ----
        float m_l = -INFINITY, s_l = 0.0f;
        float r_l[24];
        #pragma unroll
        for (int d = 0; d < 24; ++d) r_l[d] = 0.0f;
        for (int n = lo + t; n < hi; n += 64) {
            float xv[24];
            #pragma unroll
            for (int j = 0; j < 6; ++j)
                *(float4*)&xv[j * 4] = ((const float4*)(x + (size_t)n * DIM))[j];
            float e = 0.0f;
            #pragma unroll
            for (int d = 0; d < 24; ++d) e = fmaf(xv[d], qs[d], e);
            if (e > m_l) {
                float sc = expf(m_l - e);   // exp(-inf)=0 on first node: zeros stale acc
                #pragma unroll
                for (int d = 0; d < 24; ++d) r_l[d] *= sc;
                s_l *= sc;
                m_l = e;
            }
            float w = expf(e - m_l);
            s_l += w;
            #pragma unroll
            for (int d = 0; d < 24; ++d) r_l[d] = fmaf(w, xv[d], r_l[d]);
        }
        // cross-lane merge: global max, then rescale partial sums
        float m = m_l;
        #pragma unroll
        for (int off = 32; off; off >>= 1) m = fmaxf(m, __shfl_xor(m, off));
        float fac = (m_l == -INFINITY) ? 0.0f : expf(m_l - m);
        float s = s_l * fac;
        #pragma unroll
        for (int off = 32; off; off >>= 1) s += __shfl_xor(s, off);
        float denom = fmaxf(s, 1e-16f);
        #pragma unroll
        for (int d = 0; d < 24; ++d) {
            float rv = r_l[d] * fac;
            #pragma unroll
            for (int off = 32; off; off >>= 1) rv += __shfl_xor(rv, off);
            if (t == d) qs[24 + d] = rv / denom;   // compile-time d: no scratch array
        }
        __syncthreads();
    }

    // ---- head: out = relu(q_star@w_fc2+b2)@w_fc3+b3 ----
    if (t < 8) {
        float a = b_fc2[t];
        #pragma unroll
        for (int j = 0; j < 48; ++j) a = fmaf(qs[j], w_fc2[j * 8 + t], a);
        zl[t] = fmaxf(a, 0.0f);
    }
    __syncthreads();
    if (t < 2) {
        float a = b_fc3[t];
        #pragma unroll
        for (int k = 0; k < 8; ++k) a = fmaf(zl[k], w_fc3[k * 2 + t], a);
        out[(size_t)g * 2 + t] = a;
    }
}

extern "C" void kernel_launch(void* const* d_in, const int* in_sizes, int n_in,
                              void* d_out, int out_size, void* d_ws, size_t ws_size,
                              hipStream_t stream) {
    const float* x      = (const float*)d_in[0];
    const float* ea     = (const float*)d_in[1];
    const float* w_e1   = (const float*)d_in[2];
    const float* b_e1   = (const float*)d_in[3];
    const float* w_e2   = (const float*)d_in[4];
    const float* b_e2   = (const float*)d_in[5];
    const float* root   = (const float*)d_in[6];
    const float* bias_c = (const float*)d_in[7];
    const float* w_ih   = (const float*)d_in[8];
    const float* w_hh   = (const float*)d_in[9];
    const float* b_ih   = (const float*)d_in[10];
    const float* b_hh   = (const float*)d_in[11];
    const float* w_fc2  = (const float*)d_in[12];
    const float* b_fc2  = (const float*)d_in[13];
    const float* w_fc3  = (const float*)d_in[14];
    const float* b_fc3  = (const float*)d_in[15];
    const int*   eidx   = (const int*)d_in[16];
    const int*   batch  = (const int*)d_in[17];
    const int* esrc = eidx;
    const int* edst = eidx + N_EDGES;
    float* out = (float*)d_out;

    // workspace layout (bytes)
    char* ws = (char*)d_ws;
    float* agg   = (float*)(ws);                  // 4,800,000
    int*   deg   = (int*)  (ws + 4800000);        //   200,000
    float* x1    = (float*)(ws + 5789824);        // 4,800,000
    float* x2    = (float*)(ws + 10589824);       // 4,800,000
    f16*   Bz    = (f16*)  (ws + 15389824);       //   198,656 swizzled f16 w2+b2
    float* rootT = (float*)(ws + 15588480);       //     2,304 transposed root

    // zero: agg + deg
    hipMemsetAsync(ws, 0, 5000000, stream);

    // deg + Bz + rootT in one dispatch
    prep_kernel<<<1173, 256, 0, stream>>>(edst, deg, w_e2, b_e2, root, Bz, rootT);

    // layer 1 (fused edge-MLP + message + scatter; no W materialization)
    conv_kernel<<<(N_EDGES + 255) / 256, 512, 0, stream>>>(x, ea, w_e1, b_e1, Bz, esrc, edst, agg);
    combine_kernel<<<(N_NODES * 4 + 255) / 256, 256, 0, stream>>>(x, agg, deg, rootT, bias_c, x1, 1, 1);

    // layer 2 (agg was re-zeroed by combine 1)
    conv_kernel<<<(N_EDGES + 255) / 256, 512, 0, stream>>>(x1, ea, w_e1, b_e1, Bz, esrc, edst, agg);
    combine_kernel<<<(N_NODES * 4 + 255) / 256, 256, 0, stream>>>(x1, agg, deg, rootT, bias_c, x2, 0, 0);

    // fused Set2Set (3 iterations) + head: one block per graph
    s2s_kernel<<<N_GRAPHS, 64, 0, stream>>>(x2, batch, w_ih, w_hh, b_ih, b_hh,
                                            w_fc2, b_fc2, w_fc3, b_fc3, out);
}

// Round 14
// 299.666 us; speedup vs baseline: 1.0779x; 1.0779x over previous
//
#include <hip/hip_runtime.h>
#include <math.h>

#define N_NODES 50000
#define N_EDGES 200000
#define N_GRAPHS 1024
#define DIM 24
#define EF 8
#define EH 128
#define DD 576   // 24*24
#define HSTR 136 // hs row stride in f16: 128 + 8 pad (breaks stage-A/read bank conflicts)

typedef __attribute__((ext_vector_type(8))) _Float16 f16x8;
typedef __attribute__((ext_vector_type(4))) _Float16 f16x4;
typedef __attribute__((ext_vector_type(2))) _Float16 f16x2;
typedef __attribute__((ext_vector_type(4))) float float4e;
typedef _Float16 f16;

// ---------- helpers ----------
static __device__ __forceinline__ float sigm(float x) { return 1.0f / (1.0f + expf(-x)); }

// ---------- prep: deg atomics + Bz swizzle + rootT in one dispatch ----------
// blocks 0..781: deg; 782..1169: Bz; 1170..1172: rootT.
// Bz layout: [p 97][nt 2][lane 64][kk 8] f16; lane = quad*16+l16,
// element = B[k32=quad*8+kk][n=nt*16+l16] (n>=24 -> 0). p = si*24+i covers
// k-window si*32..+32 of x-feature i; p=96 = bias block. 198,656 B, L2-resident.
__global__ __launch_bounds__(256) void prep_kernel(
    const int* __restrict__ dst, int* __restrict__ deg,
    const float* __restrict__ w2, const float* __restrict__ b2,
    const float* __restrict__ root,
    f16* __restrict__ Bz, float* __restrict__ rootT)
{
    const int b = blockIdx.x, t = threadIdx.x;
    if (b < 782) {
        int i = b * 256 + t;
        if (i < N_EDGES) atomicAdd(&deg[dst[i]], 1);
        return;
    }
    if (b < 1170) {
        int idx = (b - 782) * 256 + t;
        if (idx >= 97 * 2 * 64 * 8) return;
        int kk = idx & 7, lane = (idx >> 3) & 63, nt = (idx >> 9) & 1, p = idx >> 10;
        int q = lane >> 4, l16 = lane & 15, n = nt * 16 + l16;
        float v = 0.0f;
        if (p < 96) {
            int si = p / 24, i = p % 24;
            int k = si * 32 + q * 8 + kk;
            if (n < 24) v = w2[(size_t)k * DD + i * 24 + n];
        } else {
            int i2 = q * 8 + kk;
            if (i2 < 24 && n < 24) v = b2[i2 * 24 + n];
        }
        Bz[idx] = (f16)v;
        return;
    }
    int idx = (b - 1170) * 256 + t;   // rootT[o][i] = root[i][o]
    if (idx < DD) {
        int i = idx / 24, o = idx % 24;
        rootT[o * 24 + i] = root[idx];
    }
}

// ---------- fused NNConv: h-MLP + per-edge matvec as one z-GEMM, no W ----------
// EXACT r12 form (measured 75.3us, best): block 256 / 4 waves / 128 edges,
// wave owns 32 edges (M=32), depth-4 b-prefetch, RAW in-loop barriers
// (__builtin_amdgcn_s_barrier: lockstep hint, no vmcnt drain). FROZEN.
// Structure-perturbation history: M=64 (r7: -31%), no-barrier (r10: -73%),
// 512-thr block (r13: -15%) all regressed; raw-barrier (r12: +3%) kept.
__global__ __launch_bounds__(256, 4) void conv_kernel(
    const float* __restrict__ x, const float* __restrict__ ea,
    const float* __restrict__ w1, const float* __restrict__ b1,
    const f16* __restrict__ Bz,
    const int* __restrict__ src, const int* __restrict__ dst,
    float* __restrict__ agg)
{
    __shared__ f16 hs[128 * HSTR];   // 34,816 B -> 4 blocks/CU

    const int t  = threadIdx.x;
    const int e0 = blockIdx.x * 128;

    const int lane = t & 63;
    const int wave = t >> 6;             // wave owns edges e0+wave*32 .. +32
    const int l16  = lane & 15;          // A row (edge) / B col / C col
    const int quad = lane >> 4;          // k sub-block / C row group
    const int ebase = e0 + wave * 32;

    // ---- x rows for both m-tiles -> f16 registers (issued first; L1 dedups) ----
    f16x2 xa[12], xb[12];
    {
        int ega = ebase + l16;      if (ega >= N_EDGES) ega = N_EDGES - 1;
        int egb = ebase + 16 + l16; if (egb >= N_EDGES) egb = N_EDGES - 1;
        const float* xra = x + (size_t)src[ega] * DIM;
        const float* xrb = x + (size_t)src[egb] * DIM;
        #pragma unroll
        for (int j4 = 0; j4 < 6; ++j4) {
            float4 va = *(const float4*)(xra + j4 * 4);
            float4 vb = *(const float4*)(xrb + j4 * 4);
            xa[j4 * 2]     = (f16x2){(f16)va.x, (f16)va.y};
            xa[j4 * 2 + 1] = (f16x2){(f16)va.z, (f16)va.w};
            xb[j4 * 2]     = (f16x2){(f16)vb.x, (f16)vb.y};
            xb[j4 * 2 + 1] = (f16x2){(f16)vb.z, (f16)vb.w};
        }
    }

    // ---- stage A: h = relu(ea@w1+b1) -> hs[edge][k]; thread = 4-k-slice x 16 edges ----
    {
        const int s5 = t & 31;           // k = s5*4 .. s5*4+3
        const int eb = (t >> 5) * 16;    // 16 edges starting here
        float wv[EF][4];
        #pragma unroll
        for (int j = 0; j < EF; ++j) {
            float4 v = *(const float4*)(w1 + j * EH + s5 * 4);
            wv[j][0] = v.x; wv[j][1] = v.y; wv[j][2] = v.z; wv[j][3] = v.w;
        }
        float4 bv = *(const float4*)(b1 + s5 * 4);
        const float bvv[4] = {bv.x, bv.y, bv.z, bv.w};
        #pragma unroll
        for (int e = 0; e < 16; ++e) {
            int eg = e0 + eb + e; if (eg >= N_EDGES) eg = N_EDGES - 1;  // clamp tail
            const float* ear = ea + (size_t)eg * EF;
            float4 a0 = *(const float4*)ear;
            float4 a1 = *(const float4*)(ear + 4);
            const float av[EF] = {a0.x, a0.y, a0.z, a0.w, a1.x, a1.y, a1.z, a1.w};
            float r[4] = {bvv[0], bvv[1], bvv[2], bvv[3]};
            #pragma unroll
            for (int j = 0; j < EF; ++j)
                #pragma unroll
                for (int c = 0; c < 4; ++c)
                    r[c] = fmaf(av[j], wv[j][c], r[c]);
            f16x4 hq = { (f16)fmaxf(r[0], 0.0f), (f16)fmaxf(r[1], 0.0f),
                         (f16)fmaxf(r[2], 0.0f), (f16)fmaxf(r[3], 0.0f) };
            *(f16x4*)&hs[(eb + e) * HSTR + s5 * 4] = hq;
        }
    }

    // ---- prime depth-4 b-frag pipeline (independent of LDS; overlaps barrier) ----
    const f16x8* bz = (const f16x8*)Bz + lane;
    f16x8 pb0[4], pb1[4];
    #pragma unroll
    for (int s = 0; s < 4; ++s) { pb0[s] = bz[s * 128]; pb1[s] = bz[s * 128 + 64]; }

    __syncthreads();   // correctness: hs visible to all waves (full drain OK here)

    float4e a00 = {0.f,0.f,0.f,0.f}, a01 = {0.f,0.f,0.f,0.f};
    float4e a10 = {0.f,0.f,0.f,0.f}, a11 = {0.f,0.f,0.f,0.f};

    #pragma unroll
    for (int si = 0; si < 4; ++si) {
        union { f16x8 v; f16x2 p[4]; } h0u, h1u;
        h0u.v = *(const f16x8*)&hs[(wave * 32 + l16) * HSTR + si * 32 + quad * 8];
        h1u.v = *(const f16x8*)&hs[(wave * 32 + 16 + l16) * HSTR + si * 32 + quad * 8];
        #pragma unroll
        for (int i = 0; i < 24; ++i) {
            const int p = si * 24 + i;          // compile-time
            f16x8 b0 = pb0[p & 3], b1v = pb1[p & 3];
            if (p + 4 <= 96) {                  // prefetch 4 steps ahead into freed slot
                pb0[p & 3] = bz[(p + 4) * 128];
                pb1[p & 3] = bz[(p + 4) * 128 + 64];
            }
            f16 xea = (i & 1) ? xa[i >> 1][1] : xa[i >> 1][0];
            f16 xeb = (i & 1) ? xb[i >> 1][1] : xb[i >> 1][0];
            f16x2 xa2 = {xea, xea}, xb2 = {xeb, xeb};
            union { f16x8 v; f16x2 p[4]; } a0u, a1u;
            #pragma unroll
            for (int j = 0; j < 4; ++j) {
                a0u.p[j] = h0u.p[j] * xa2;      // v_pk_mul_f16
                a1u.p[j] = h1u.p[j] * xb2;
            }
            a00 = __builtin_amdgcn_mfma_f32_16x16x32_f16(a0u.v, b0,  a00, 0, 0, 0);
            a10 = __builtin_amdgcn_mfma_f32_16x16x32_f16(a1u.v, b0,  a10, 0, 0, 0);
            a01 = __builtin_amdgcn_mfma_f32_16x16x32_f16(a0u.v, b1v, a01, 0, 0, 0);
            a11 = __builtin_amdgcn_mfma_f32_16x16x32_f16(a1u.v, b1v, a11, 0, 0, 0);
            // lockstep hint only (no data dep): RAW barrier, no vmcnt drain.
            if ((p % 12) == 11) __builtin_amdgcn_s_barrier();
        }
    }

    // ---- bias step (p = 96): A = x row slices, B = b2 reshaped; frags in slot 0 ----
    {
        union { f16x8 v; f16x2 p[4]; } a0u, a1u;
        f16x2 z2 = {(f16)0.f, (f16)0.f};
        if (quad == 0)      { a0u.p[0]=xa[0]; a0u.p[1]=xa[1]; a0u.p[2]=xa[2];  a0u.p[3]=xa[3];
                              a1u.p[0]=xb[0]; a1u.p[1]=xb[1]; a1u.p[2]=xb[2];  a1u.p[3]=xb[3];  }
        else if (quad == 1) { a0u.p[0]=xa[4]; a0u.p[1]=xa[5]; a0u.p[2]=xa[6];  a0u.p[3]=xa[7];
                              a1u.p[0]=xb[4]; a1u.p[1]=xb[5]; a1u.p[2]=xb[6];  a1u.p[3]=xb[7];  }
        else if (quad == 2) { a0u.p[0]=xa[8]; a0u.p[1]=xa[9]; a0u.p[2]=xa[10]; a0u.p[3]=xa[11];
                              a1u.p[0]=xb[8]; a1u.p[1]=xb[9]; a1u.p[2]=xb[10]; a1u.p[3]=xb[11]; }
        else                { a0u.p[0]=z2; a0u.p[1]=z2; a0u.p[2]=z2; a0u.p[3]=z2;
                              a1u.p[0]=z2; a1u.p[1]=z2; a1u.p[2]=z2; a1u.p[3]=z2; }
        a00 = __builtin_amdgcn_mfma_f32_16x16x32_f16(a0u.v, pb0[0], a00, 0, 0, 0);
        a10 = __builtin_amdgcn_mfma_f32_16x16x32_f16(a1u.v, pb0[0], a10, 0, 0, 0);
        a01 = __builtin_amdgcn_mfma_f32_16x16x32_f16(a0u.v, pb1[0], a01, 0, 0, 0);
        a11 = __builtin_amdgcn_mfma_f32_16x16x32_f16(a1u.v, pb1[0], a11, 0, 0, 0);
    }

    // ---- scatter: C row = quad*4+r (edge), col = l16 (+16) = o ----
    #pragma unroll
    for (int r = 0; r < 4; ++r) {
        int er = ebase + quad * 4 + r;
        if (er < N_EDGES) {
            int d = dst[er];
            atomicAdd(&agg[(size_t)d * DIM + l16], a00[r]);
            if (l16 < 8) atomicAdd(&agg[(size_t)d * DIM + 16 + l16], a01[r]);
        }
        int er2 = ebase + 16 + quad * 4 + r;
        if (er2 < N_EDGES) {
            int d = dst[er2];
            atomicAdd(&agg[(size_t)d * DIM + l16], a10[r]);
            if (l16 < 8) atomicAdd(&agg[(size_t)d * DIM + 16 + l16], a11[r]);
        }
    }
}

// ---------- combine: x_out = [relu](agg/max(deg,1) + x_in@rootT^T + bias) ----------
// Vectorized: thread = (node, quarter of 6 outputs); float4 x/rootT loads.
// zero_agg=1: write agg=0 after reading (folds the inter-layer memset).
__global__ __launch_bounds__(256) void combine_kernel(
    const float* __restrict__ x_in, float* __restrict__ agg,
    const int* __restrict__ deg, const float* __restrict__ rootT,
    const float* __restrict__ bias, float* __restrict__ x_out,
    int do_relu, int zero_agg)
{
    int gid = blockIdx.x * 256 + threadIdx.x;
    int v = gid >> 2, q = gid & 3;
    if (v >= N_NODES) return;
    const int o0 = q * 6;

    float xv[24];
    const float4* xr = (const float4*)(x_in + (size_t)v * DIM);
    #pragma unroll
    for (int j = 0; j < 6; ++j) *(float4*)&xv[j * 4] = xr[j];

    int dg = deg[v];
    float dinv = 1.0f / (dg > 0 ? (float)dg : 1.0f);
    float* aggr = agg + (size_t)v * DIM + o0;

    float r[6];
    #pragma unroll
    for (int u = 0; u < 6; ++u) {
        int o = o0 + u;
        float a = aggr[u] * dinv + bias[o];
        const float4* rt = (const float4*)(rootT + o * 24);
        #pragma unroll
        for (int j = 0; j < 6; ++j) {
            float4 w = rt[j];
            a = fmaf(xv[j*4+0], w.x, a); a = fmaf(xv[j*4+1], w.y, a);
            a = fmaf(xv[j*4+2], w.z, a); a = fmaf(xv[j*4+3], w.w, a);
        }
        r[u] = do_relu ? fmaxf(a, 0.0f) : a;
    }
    if (zero_agg) {
        #pragma unroll
        for (int u = 0; u < 6; ++u) aggr[u] = 0.0f;
    }
    float* xo = x_out + (size_t)v * DIM + o0;
    #pragma unroll
    for (int u = 0; u < 6; ++u) xo[u] = r[u];
}

// ---------- fused Set2Set (3x LSTM+attention) + head: one block per graph ----------
__global__ __launch_bounds__(64) void s2s_kernel(
    const float* __restrict__ x, const int* __restrict__ batch,
    const float* __restrict__ w_ih, const float* __restrict__ w_hh,
    const float* __restrict__ b_ih, const float* __restrict__ b_hh,
    const float* __restrict__ w_fc2, const float* __restrict__ b_fc2,
    const float* __restrict__ w_fc3, const float* __restrict__ b_fc3,
    float* __restrict__ out)
{
    const int g = blockIdx.x;
    const int t = threadIdx.x;     // 64 = 1 wave
    __shared__ float qs[48];       // q_star = [q | r]
    __shared__ float hh[24], cc[24], gates[96], zl[8];
    __shared__ int s_lo, s_hi;

    if (t == 0) {
        int lo = 0, hi = N_NODES;
        while (lo < hi) { int m = (lo + hi) >> 1; if (batch[m] < g) lo = m + 1; else hi = m; }
        s_lo = lo;
        int lo2 = lo; hi = N_NODES;
        while (lo2 < hi) { int m = (lo2 + hi) >> 1; if (batch[m] <= g) lo2 = m + 1; else hi = m; }
        s_hi = lo2;
    }
    if (t < 48) qs[t] = 0.0f;
    if (t < 24) { hh[t] = 0.0f; cc[t] = 0.0f; }
    __syncthreads();
    const int lo = s_lo, hi = s_hi;

    for (int it = 0; it < 3; ++it) {
        // ---- LSTM gates (float4 weight loads) ----
        for (int rr = t; rr < 96; rr += 64) {
            float a = b_ih[rr] + b_hh[rr];
            const float* wi = w_ih + (size_t)rr * 48;
            const float* wh = w_hh + (size_t)rr * 24;
            #pragma unroll
            for (int j4 = 0; j4 < 12; ++j4) {
                float4 w = *(const float4*)(wi + j4 * 4);
                a = fmaf(qs[j4*4+0], w.x, a); a = fmaf(qs[j4*4+1], w.y, a);
                a = fmaf(qs[j4*4+2], w.z, a); a = fmaf(qs[j4*4+3], w.w, a);
            }
            #pragma unroll
            for (int j4 = 0; j4 < 6; ++j4) {
                float4 w = *(const float4*)(wh + j4 * 4);
                a = fmaf(hh[j4*4+0], w.x, a); a = fmaf(hh[j4*4+1], w.y, a);
                a = fmaf(hh[j4*4+2], w.z, a); a = fmaf(hh[j4*4+3], w.w, a);
            }
            gates[rr] = a;
        }
        __syncthreads();
        if (t < 24) {
            float c = sigm(gates[24 + t]) * cc[t] + sigm(gates[t]) * tanhf(gates[48 + t]);
            cc[t] = c;
            float h = sigm(gates[72 + t]) * tanhf(c);
            hh[t] = h;
            qs[t] = h;               // q part of q_star
        }
        __syncthreads();

        // ---- attention: single-pass online softmax over this graph's nodes ----
        float m_l = -INFINITY, s_l = 0.0f;
        float r_l[24];
        #pragma unroll
        for (int d = 0; d < 24; ++d) r_l[d] = 0.0f;
        for (int n = lo + t; n < hi; n += 64) {
            float xv[24];
            #pragma unroll
            for (int j = 0; j < 6; ++j)
                *(float4*)&xv[j * 4] = ((const float4*)(x + (size_t)n * DIM))[j];
            float e = 0.0f;
            #pragma unroll
            for (int d = 0; d < 24; ++d) e = fmaf(xv[d], qs[d], e);
            if (e > m_l) {
                float sc = expf(m_l - e);   // exp(-inf)=0 on first node: zeros stale acc
                #pragma unroll
                for (int d = 0; d < 24; ++d) r_l[d] *= sc;
                s_l *= sc;
                m_l = e;
            }
            float w = expf(e - m_l);
            s_l += w;
            #pragma unroll
            for (int d = 0; d < 24; ++d) r_l[d] = fmaf(w, xv[d], r_l[d]);
        }
        // cross-lane merge: global max, then rescale partial sums
        float m = m_l;
        #pragma unroll
        for (int off = 32; off; off >>= 1) m = fmaxf(m, __shfl_xor(m, off));
        float fac = (m_l == -INFINITY) ? 0.0f : expf(m_l - m);
        float s = s_l * fac;
        #pragma unroll
        for (int off = 32; off; off >>= 1) s += __shfl_xor(s, off);
        float denom = fmaxf(s, 1e-16f);
        #pragma unroll
        for (int d = 0; d < 24; ++d) {
            float rv = r_l[d] * fac;
            #pragma unroll
            for (int off = 32; off; off >>= 1) rv += __shfl_xor(rv, off);
            if (t == d) qs[24 + d] = rv / denom;   // compile-time d: no scratch array
        }
        __syncthreads();
    }

    // ---- head: out = relu(q_star@w_fc2+b2)@w_fc3+b3 ----
    if (t < 8) {
        float a = b_fc2[t];
        #pragma unroll
        for (int j = 0; j < 48; ++j) a = fmaf(qs[j], w_fc2[j * 8 + t], a);
        zl[t] = fmaxf(a, 0.0f);
    }
    __syncthreads();
    if (t < 2) {
        float a = b_fc3[t];
        #pragma unroll
        for (int k = 0; k < 8; ++k) a = fmaf(zl[k], w_fc3[k * 2 + t], a);
        out[(size_t)g * 2 + t] = a;
    }
}

extern "C" void kernel_launch(void* const* d_in, const int* in_sizes, int n_in,
                              void* d_out, int out_size, void* d_ws, size_t ws_size,
                              hipStream_t stream) {
    const float* x      = (const float*)d_in[0];
    const float* ea     = (const float*)d_in[1];
    const float* w_e1   = (const float*)d_in[2];
    const float* b_e1   = (const float*)d_in[3];
    const float* w_e2   = (const float*)d_in[4];
    const float* b_e2   = (const float*)d_in[5];
    const float* root   = (const float*)d_in[6];
    const float* bias_c = (const float*)d_in[7];
    const float* w_ih   = (const float*)d_in[8];
    const float* w_hh   = (const float*)d_in[9];
    const float* b_ih   = (const float*)d_in[10];
    const float* b_hh   = (const float*)d_in[11];
    const float* w_fc2  = (const float*)d_in[12];
    const float* b_fc2  = (const float*)d_in[13];
    const float* w_fc3  = (const float*)d_in[14];
    const float* b_fc3  = (const float*)d_in[15];
    const int*   eidx   = (const int*)d_in[16];
    const int*   batch  = (const int*)d_in[17];
    const int* esrc = eidx;
    const int* edst = eidx + N_EDGES;
    float* out = (float*)d_out;

    // workspace layout (bytes)
    char* ws = (char*)d_ws;
    float* agg   = (float*)(ws);                  // 4,800,000
    int*   deg   = (int*)  (ws + 4800000);        //   200,000
    float* x1    = (float*)(ws + 5789824);        // 4,800,000
    float* x2    = (float*)(ws + 10589824);       // 4,800,000
    f16*   Bz    = (f16*)  (ws + 15389824);       //   198,656 swizzled f16 w2+b2
    float* rootT = (float*)(ws + 15588480);       //     2,304 transposed root

    // zero: agg + deg
    hipMemsetAsync(ws, 0, 5000000, stream);

    // deg + Bz + rootT in one dispatch
    prep_kernel<<<1173, 256, 0, stream>>>(edst, deg, w_e2, b_e2, root, Bz, rootT);

    // layer 1 (fused edge-MLP + message + scatter; no W materialization)
    conv_kernel<<<(N_EDGES + 127) / 128, 256, 0, stream>>>(x, ea, w_e1, b_e1, Bz, esrc, edst, agg);
    combine_kernel<<<(N_NODES * 4 + 255) / 256, 256, 0, stream>>>(x, agg, deg, rootT, bias_c, x1, 1, 1);

    // layer 2 (agg was re-zeroed by combine 1)
    conv_kernel<<<(N_EDGES + 127) / 128, 256, 0, stream>>>(x1, ea, w_e1, b_e1, Bz, esrc, edst, agg);
    combine_kernel<<<(N_NODES * 4 + 255) / 256, 256, 0, stream>>>(x1, agg, deg, rootT, bias_c, x2, 0, 0);

    // fused Set2Set (3 iterations) + head: one block per graph
    s2s_kernel<<<N_GRAPHS, 64, 0, stream>>>(x2, batch, w_ih, w_hh, b_ih, b_hh,
                                            w_fc2, b_fc2, w_fc3, b_fc3, out);
}

// Round 15
// 295.489 us; speedup vs baseline: 1.0931x; 1.0141x over previous
//
#include <hip/hip_runtime.h>
#include <math.h>

#define N_NODES 50000
#define N_EDGES 200000
#define N_GRAPHS 1024
#define DIM 24
#define EF 8
#define EH 128
#define DD 576   // 24*24
#define HSTR 136 // hs row stride in f16: 128 + 8 pad (breaks stage-A/read bank conflicts)

typedef __attribute__((ext_vector_type(8))) _Float16 f16x8;
typedef __attribute__((ext_vector_type(4))) _Float16 f16x4;
typedef __attribute__((ext_vector_type(2))) _Float16 f16x2;
typedef __attribute__((ext_vector_type(4))) float float4e;
typedef _Float16 f16;

// ---------- helpers ----------
static __device__ __forceinline__ float sigm(float x) { return 1.0f / (1.0f + expf(-x)); }

// ---------- prep: deg + Bz swizzle + rootT + graph-offset table, one dispatch ----------
// blocks 0..781: deg; 782..1169: Bz; 1170..1172: rootT; 1173..1368: offs.
// Bz layout: [p 97][nt 2][lane 64][kk 8] f16; lane = quad*16+l16,
// element = B[k32=quad*8+kk][n=nt*16+l16] (n>=24 -> 0). p = si*24+i covers
// k-window si*32..+32 of x-feature i; p=96 = bias block. 198,656 B, L2-resident.
// offs[g] = first node index of graph g (lower bound in sorted batch);
// offs[1024] = N_NODES. Empty graphs get offs[g]==offs[g+1]. Replaces the
// per-block serial binary search in s2s (2x17 dependent global loads by
// lane 0 while 63 lanes idle).
__global__ __launch_bounds__(256) void prep_kernel(
    const int* __restrict__ dst, int* __restrict__ deg,
    const float* __restrict__ w2, const float* __restrict__ b2,
    const float* __restrict__ root, const int* __restrict__ batch,
    f16* __restrict__ Bz, float* __restrict__ rootT, int* __restrict__ offs)
{
    const int b = blockIdx.x, t = threadIdx.x;
    if (b < 782) {
        int i = b * 256 + t;
        if (i < N_EDGES) atomicAdd(&deg[dst[i]], 1);
        return;
    }
    if (b < 1170) {
        int idx = (b - 782) * 256 + t;
        if (idx >= 97 * 2 * 64 * 8) return;
        int kk = idx & 7, lane = (idx >> 3) & 63, nt = (idx >> 9) & 1, p = idx >> 10;
        int q = lane >> 4, l16 = lane & 15, n = nt * 16 + l16;
        float v = 0.0f;
        if (p < 96) {
            int si = p / 24, i = p % 24;
            int k = si * 32 + q * 8 + kk;
            if (n < 24) v = w2[(size_t)k * DD + i * 24 + n];
        } else {
            int i2 = q * 8 + kk;
            if (i2 < 24 && n < 24) v = b2[i2 * 24 + n];
        }
        Bz[idx] = (f16)v;
        return;
    }
    if (b < 1173) {
        int idx = (b - 1170) * 256 + t;   // rootT[o][i] = root[i][o]
        if (idx < DD) {
            int i = idx / 24, o = idx % 24;
            rootT[o * 24 + i] = root[idx];
        }
        return;
    }
    // ---- graph offsets from sorted batch ----
    int n = (b - 1173) * 256 + t;
    if (n >= N_NODES) return;
    int b0 = batch[n];
    if (n == 0)
        for (int g = 0; g <= b0; ++g) offs[g] = 0;
    int b1 = (n + 1 < N_NODES) ? batch[n + 1] : N_GRAPHS;
    for (int g = b0 + 1; g <= b1; ++g) offs[g] = n + 1;
}

// ---------- fused NNConv: h-MLP + per-edge matvec as one z-GEMM, no W ----------
// EXACT r12 form (measured 75.3us, best): block 256 / 4 waves / 128 edges,
// wave owns 32 edges (M=32), depth-4 b-prefetch, RAW in-loop barriers
// (__builtin_amdgcn_s_barrier: lockstep hint, no vmcnt drain). FROZEN.
// Structure-perturbation history: M=64 (r7: -31%), no-barrier (r10: -73%),
// 512-thr block (r13: -15%) all regressed; raw-barrier (r12: +3%) kept.
__global__ __launch_bounds__(256, 4) void conv_kernel(
    const float* __restrict__ x, const float* __restrict__ ea,
    const float* __restrict__ w1, const float* __restrict__ b1,
    const f16* __restrict__ Bz,
    const int* __restrict__ src, const int* __restrict__ dst,
    float* __restrict__ agg)
{
    __shared__ f16 hs[128 * HSTR];   // 34,816 B -> 4 blocks/CU

    const int t  = threadIdx.x;
    const int e0 = blockIdx.x * 128;

    const int lane = t & 63;
    const int wave = t >> 6;             // wave owns edges e0+wave*32 .. +32
    const int l16  = lane & 15;          // A row (edge) / B col / C col
    const int quad = lane >> 4;          // k sub-block / C row group
    const int ebase = e0 + wave * 32;

    // ---- x rows for both m-tiles -> f16 registers (issued first; L1 dedups) ----
    f16x2 xa[12], xb[12];
    {
        int ega = ebase + l16;      if (ega >= N_EDGES) ega = N_EDGES - 1;
        int egb = ebase + 16 + l16; if (egb >= N_EDGES) egb = N_EDGES - 1;
        const float* xra = x + (size_t)src[ega] * DIM;
        const float* xrb = x + (size_t)src[egb] * DIM;
        #pragma unroll
        for (int j4 = 0; j4 < 6; ++j4) {
            float4 va = *(const float4*)(xra + j4 * 4);
            float4 vb = *(const float4*)(xrb + j4 * 4);
            xa[j4 * 2]     = (f16x2){(f16)va.x, (f16)va.y};
            xa[j4 * 2 + 1] = (f16x2){(f16)va.z, (f16)va.w};
            xb[j4 * 2]     = (f16x2){(f16)vb.x, (f16)vb.y};
            xb[j4 * 2 + 1] = (f16x2){(f16)vb.z, (f16)vb.w};
        }
    }

    // ---- stage A: h = relu(ea@w1+b1) -> hs[edge][k]; thread = 4-k-slice x 16 edges ----
    {
        const int s5 = t & 31;           // k = s5*4 .. s5*4+3
        const int eb = (t >> 5) * 16;    // 16 edges starting here
        float wv[EF][4];
        #pragma unroll
        for (int j = 0; j < EF; ++j) {
            float4 v = *(const float4*)(w1 + j * EH + s5 * 4);
            wv[j][0] = v.x; wv[j][1] = v.y; wv[j][2] = v.z; wv[j][3] = v.w;
        }
        float4 bv = *(const float4*)(b1 + s5 * 4);
        const float bvv[4] = {bv.x, bv.y, bv.z, bv.w};
        #pragma unroll
        for (int e = 0; e < 16; ++e) {
            int eg = e0 + eb + e; if (eg >= N_EDGES) eg = N_EDGES - 1;  // clamp tail
            const float* ear = ea + (size_t)eg * EF;
            float4 a0 = *(const float4*)ear;
            float4 a1 = *(const float4*)(ear + 4);
            const float av[EF] = {a0.x, a0.y, a0.z, a0.w, a1.x, a1.y, a1.z, a1.w};
            float r[4] = {bvv[0], bvv[1], bvv[2], bvv[3]};
            #pragma unroll
            for (int j = 0; j < EF; ++j)
                #pragma unroll
                for (int c = 0; c < 4; ++c)
                    r[c] = fmaf(av[j], wv[j][c], r[c]);
            f16x4 hq = { (f16)fmaxf(r[0], 0.0f), (f16)fmaxf(r[1], 0.0f),
                         (f16)fmaxf(r[2], 0.0f), (f16)fmaxf(r[3], 0.0f) };
            *(f16x4*)&hs[(eb + e) * HSTR + s5 * 4] = hq;
        }
    }

    // ---- prime depth-4 b-frag pipeline (independent of LDS; overlaps barrier) ----
    const f16x8* bz = (const f16x8*)Bz + lane;
    f16x8 pb0[4], pb1[4];
    #pragma unroll
    for (int s = 0; s < 4; ++s) { pb0[s] = bz[s * 128]; pb1[s] = bz[s * 128 + 64]; }

    __syncthreads();   // correctness: hs visible to all waves (full drain OK here)

    float4e a00 = {0.f,0.f,0.f,0.f}, a01 = {0.f,0.f,0.f,0.f};
    float4e a10 = {0.f,0.f,0.f,0.f}, a11 = {0.f,0.f,0.f,0.f};

    #pragma unroll
    for (int si = 0; si < 4; ++si) {
        union { f16x8 v; f16x2 p[4]; } h0u, h1u;
        h0u.v = *(const f16x8*)&hs[(wave * 32 + l16) * HSTR + si * 32 + quad * 8];
        h1u.v = *(const f16x8*)&hs[(wave * 32 + 16 + l16) * HSTR + si * 32 + quad * 8];
        #pragma unroll
        for (int i = 0; i < 24; ++i) {
            const int p = si * 24 + i;          // compile-time
            f16x8 b0 = pb0[p & 3], b1v = pb1[p & 3];
            if (p + 4 <= 96) {                  // prefetch 4 steps ahead into freed slot
                pb0[p & 3] = bz[(p + 4) * 128];
                pb1[p & 3] = bz[(p + 4) * 128 + 64];
            }
            f16 xea = (i & 1) ? xa[i >> 1][1] : xa[i >> 1][0];
            f16 xeb = (i & 1) ? xb[i >> 1][1] : xb[i >> 1][0];
            f16x2 xa2 = {xea, xea}, xb2 = {xeb, xeb};
            union { f16x8 v; f16x2 p[4]; } a0u, a1u;
            #pragma unroll
            for (int j = 0; j < 4; ++j) {
                a0u.p[j] = h0u.p[j] * xa2;      // v_pk_mul_f16
                a1u.p[j] = h1u.p[j] * xb2;
            }
            a00 = __builtin_amdgcn_mfma_f32_16x16x32_f16(a0u.v, b0,  a00, 0, 0, 0);
            a10 = __builtin_amdgcn_mfma_f32_16x16x32_f16(a1u.v, b0,  a10, 0, 0, 0);
            a01 = __builtin_amdgcn_mfma_f32_16x16x32_f16(a0u.v, b1v, a01, 0, 0, 0);
            a11 = __builtin_amdgcn_mfma_f32_16x16x32_f16(a1u.v, b1v, a11, 0, 0, 0);
            // lockstep hint only (no data dep): RAW barrier, no vmcnt drain.
            if ((p % 12) == 11) __builtin_amdgcn_s_barrier();
        }
    }

    // ---- bias step (p = 96): A = x row slices, B = b2 reshaped; frags in slot 0 ----
    {
        union { f16x8 v; f16x2 p[4]; } a0u, a1u;
        f16x2 z2 = {(f16)0.f, (f16)0.f};
        if (quad == 0)      { a0u.p[0]=xa[0]; a0u.p[1]=xa[1]; a0u.p[2]=xa[2];  a0u.p[3]=xa[3];
                              a1u.p[0]=xb[0]; a1u.p[1]=xb[1]; a1u.p[2]=xb[2];  a1u.p[3]=xb[3];  }
        else if (quad == 1) { a0u.p[0]=xa[4]; a0u.p[1]=xa[5]; a0u.p[2]=xa[6];  a0u.p[3]=xa[7];
                              a1u.p[0]=xb[4]; a1u.p[1]=xb[5]; a1u.p[2]=xb[6];  a1u.p[3]=xb[7];  }
        else if (quad == 2) { a0u.p[0]=xa[8]; a0u.p[1]=xa[9]; a0u.p[2]=xa[10]; a0u.p[3]=xa[11];
                              a1u.p[0]=xb[8]; a1u.p[1]=xb[9]; a1u.p[2]=xb[10]; a1u.p[3]=xb[11]; }
        else                { a0u.p[0]=z2; a0u.p[1]=z2; a0u.p[2]=z2; a0u.p[3]=z2;
                              a1u.p[0]=z2; a1u.p[1]=z2; a1u.p[2]=z2; a1u.p[3]=z2; }
        a00 = __builtin_amdgcn_mfma_f32_16x16x32_f16(a0u.v, pb0[0], a00, 0, 0, 0);
        a10 = __builtin_amdgcn_mfma_f32_16x16x32_f16(a1u.v, pb0[0], a10, 0, 0, 0);
        a01 = __builtin_amdgcn_mfma_f32_16x16x32_f16(a0u.v, pb1[0], a01, 0, 0, 0);
        a11 = __builtin_amdgcn_mfma_f32_16x16x32_f16(a1u.v, pb1[0], a11, 0, 0, 0);
    }

    // ---- scatter: C row = quad*4+r (edge), col = l16 (+16) = o ----
    #pragma unroll
    for (int r = 0; r < 4; ++r) {
        int er = ebase + quad * 4 + r;
        if (er < N_EDGES) {
            int d = dst[er];
            atomicAdd(&agg[(size_t)d * DIM + l16], a00[r]);
            if (l16 < 8) atomicAdd(&agg[(size_t)d * DIM + 16 + l16], a01[r]);
        }
        int er2 = ebase + 16 + quad * 4 + r;
        if (er2 < N_EDGES) {
            int d = dst[er2];
            atomicAdd(&agg[(size_t)d * DIM + l16], a10[r]);
            if (l16 < 8) atomicAdd(&agg[(size_t)d * DIM + 16 + l16], a11[r]);
        }
    }
}

// ---------- combine: x_out = [relu](agg/max(deg,1) + x_in@rootT^T + bias) ----------
// Vectorized: thread = (node, quarter of 6 outputs); float4 x/rootT loads.
// zero_agg=1: write agg=0 after reading (folds the inter-layer memset).
__global__ __launch_bounds__(256) void combine_kernel(
    const float* __restrict__ x_in, float* __restrict__ agg,
    const int* __restrict__ deg, const float* __restrict__ rootT,
    const float* __restrict__ bias, float* __restrict__ x_out,
    int do_relu, int zero_agg)
{
    int gid = blockIdx.x * 256 + threadIdx.x;
    int v = gid >> 2, q = gid & 3;
    if (v >= N_NODES) return;
    const int o0 = q * 6;

    float xv[24];
    const float4* xr = (const float4*)(x_in + (size_t)v * DIM);
    #pragma unroll
    for (int j = 0; j < 6; ++j) *(float4*)&xv[j * 4] = xr[j];

    int dg = deg[v];
    float dinv = 1.0f / (dg > 0 ? (float)dg : 1.0f);
    float* aggr = agg + (size_t)v * DIM + o0;

    float r[6];
    #pragma unroll
    for (int u = 0; u < 6; ++u) {
        int o = o0 + u;
        float a = aggr[u] * dinv + bias[o];
        const float4* rt = (const float4*)(rootT + o * 24);
        #pragma unroll
        for (int j = 0; j < 6; ++j) {
            float4 w = rt[j];
            a = fmaf(xv[j*4+0], w.x, a); a = fmaf(xv[j*4+1], w.y, a);
            a = fmaf(xv[j*4+2], w.z, a); a = fmaf(xv[j*4+3], w.w, a);
        }
        r[u] = do_relu ? fmaxf(a, 0.0f) : a;
    }
    if (zero_agg) {
        #pragma unroll
        for (int u = 0; u < 6; ++u) aggr[u] = 0.0f;
    }
    float* xo = x_out + (size_t)v * DIM + o0;
    #pragma unroll
    for (int u = 0; u < 6; ++u) xo[u] = r[u];
}

// ---------- fused Set2Set (3x LSTM+attention) + head: one block per graph ----------
// Round-15 change: graph node-range comes from the precomputed offs table
// (2 L2-hot loads) instead of 2x17-iteration serial binary search by lane 0
// (~10-30K dependent-load cycles per block while 63 lanes idle).
__global__ __launch_bounds__(64) void s2s_kernel(
    const float* __restrict__ x, const int* __restrict__ offs,
    const float* __restrict__ w_ih, const float* __restrict__ w_hh,
    const float* __restrict__ b_ih, const float* __restrict__ b_hh,
    const float* __restrict__ w_fc2, const float* __restrict__ b_fc2,
    const float* __restrict__ w_fc3, const float* __restrict__ b_fc3,
    float* __restrict__ out)
{
    const int g = blockIdx.x;
    const int t = threadIdx.x;     // 64 = 1 wave
    __shared__ float qs[48];       // q_star = [q | r]
    __shared__ float hh[24], cc[24], gates[96], zl[8];

    const int lo = offs[g], hi = offs[g + 1];

    if (t < 48) qs[t] = 0.0f;
    if (t < 24) { hh[t] = 0.0f; cc[t] = 0.0f; }
    __syncthreads();

    for (int it = 0; it < 3; ++it) {
        // ---- LSTM gates (float4 weight loads) ----
        for (int rr = t; rr < 96; rr += 64) {
            float a = b_ih[rr] + b_hh[rr];
            const float* wi = w_ih + (size_t)rr * 48;
            const float* wh = w_hh + (size_t)rr * 24;
            #pragma unroll
            for (int j4 = 0; j4 < 12; ++j4) {
                float4 w = *(const float4*)(wi + j4 * 4);
                a = fmaf(qs[j4*4+0], w.x, a); a = fmaf(qs[j4*4+1], w.y, a);
                a = fmaf(qs[j4*4+2], w.z, a); a = fmaf(qs[j4*4+3], w.w, a);
            }
            #pragma unroll
            for (int j4 = 0; j4 < 6; ++j4) {
                float4 w = *(const float4*)(wh + j4 * 4);
                a = fmaf(hh[j4*4+0], w.x, a); a = fmaf(hh[j4*4+1], w.y, a);
                a = fmaf(hh[j4*4+2], w.z, a); a = fmaf(hh[j4*4+3], w.w, a);
            }
            gates[rr] = a;
        }
        __syncthreads();
        if (t < 24) {
            float c = sigm(gates[24 + t]) * cc[t] + sigm(gates[t]) * tanhf(gates[48 + t]);
            cc[t] = c;
            float h = sigm(gates[72 + t]) * tanhf(c);
            hh[t] = h;
            qs[t] = h;               // q part of q_star
        }
        __syncthreads();

        // ---- attention: single-pass online softmax over this graph's nodes ----
        float m_l = -INFINITY, s_l = 0.0f;
        float r_l[24];
        #pragma unroll
        for (int d = 0; d < 24; ++d) r_l[d] = 0.0f;
        for (int n = lo + t; n < hi; n += 64) {
            float xv[24];
            #pragma unroll
            for (int j = 0; j < 6; ++j)
                *(float4*)&xv[j * 4] = ((const float4*)(x + (size_t)n * DIM))[j];
            float e = 0.0f;
            #pragma unroll
            for (int d = 0; d < 24; ++d) e = fmaf(xv[d], qs[d], e);
            if (e > m_l) {
                float sc = expf(m_l - e);   // exp(-inf)=0 on first node: zeros stale acc
                #pragma unroll
                for (int d = 0; d < 24; ++d) r_l[d] *= sc;
                s_l *= sc;
                m_l = e;
            }
            float w = expf(e - m_l);
            s_l += w;
            #pragma unroll
            for (int d = 0; d < 24; ++d) r_l[d] = fmaf(w, xv[d], r_l[d]);
        }
        // cross-lane merge: global max, then rescale partial sums
        float m = m_l;
        #pragma unroll
        for (int off = 32; off; off >>= 1) m = fmaxf(m, __shfl_xor(m, off));
        float fac = (m_l == -INFINITY) ? 0.0f : expf(m_l - m);
        float s = s_l * fac;
        #pragma unroll
        for (int off = 32; off; off >>= 1) s += __shfl_xor(s, off);
        float denom = fmaxf(s, 1e-16f);
        #pragma unroll
        for (int d = 0; d < 24; ++d) {
            float rv = r_l[d] * fac;
            #pragma unroll
            for (int off = 32; off; off >>= 1) rv += __shfl_xor(rv, off);
            if (t == d) qs[24 + d] = rv / denom;   // compile-time d: no scratch array
        }
        __syncthreads();
    }

    // ---- head: out = relu(q_star@w_fc2+b2)@w_fc3+b3 ----
    if (t < 8) {
        float a = b_fc2[t];
        #pragma unroll
        for (int j = 0; j < 48; ++j) a = fmaf(qs[j], w_fc2[j * 8 + t], a);
        zl[t] = fmaxf(a, 0.0f);
    }
    __syncthreads();
    if (t < 2) {
        float a = b_fc3[t];
        #pragma unroll
        for (int k = 0; k < 8; ++k) a = fmaf(zl[k], w_fc3[k * 2 + t], a);
        out[(size_t)g * 2 + t] = a;
    }
}

extern "C" void kernel_launch(void* const* d_in, const int* in_sizes, int n_in,
                              void* d_out, int out_size, void* d_ws, size_t ws_size,
                              hipStream_t stream) {
    const float* x      = (const float*)d_in[0];
    const float* ea     = (const float*)d_in[1];
    const float* w_e1   = (const float*)d_in[2];
    const float* b_e1   = (const float*)d_in[3];
    const float* w_e2   = (const float*)d_in[4];
    const float* b_e2   = (const float*)d_in[5];
    const float* root   = (const float*)d_in[6];
    const float* bias_c = (const float*)d_in[7];
    const float* w_ih   = (const float*)d_in[8];
    const float* w_hh   = (const float*)d_in[9];
    const float* b_ih   = (const float*)d_in[10];
    const float* b_hh   = (const float*)d_in[11];
    const float* w_fc2  = (const float*)d_in[12];
    const float* b_fc2  = (const float*)d_in[13];
    const float* w_fc3  = (const float*)d_in[14];
    const float* b_fc3  = (const float*)d_in[15];
    const int*   eidx   = (const int*)d_in[16];
    const int*   batch  = (const int*)d_in[17];
    const int* esrc = eidx;
    const int* edst = eidx + N_EDGES;
    float* out = (float*)d_out;

    // workspace layout (bytes)
    char* ws = (char*)d_ws;
    float* agg   = (float*)(ws);                  // 4,800,000
    int*   deg   = (int*)  (ws + 4800000);        //   200,000
    float* x1    = (float*)(ws + 5789824);        // 4,800,000
    float* x2    = (float*)(ws + 10589824);       // 4,800,000
    f16*   Bz    = (f16*)  (ws + 15389824);       //   198,656 swizzled f16 w2+b2
    float* rootT = (float*)(ws + 15588480);       //     2,304 transposed root
    int*   offs  = (int*)  (ws + 15590784);       //     4,100 graph offsets [1025]

    // zero: agg + deg
    hipMemsetAsync(ws, 0, 5000000, stream);

    // deg + Bz + rootT + offs in one dispatch
    prep_kernel<<<1369, 256, 0, stream>>>(edst, deg, w_e2, b_e2, root, batch, Bz, rootT, offs);

    // layer 1 (fused edge-MLP + message + scatter; no W materialization)
    conv_kernel<<<(N_EDGES + 127) / 128, 256, 0, stream>>>(x, ea, w_e1, b_e1, Bz, esrc, edst, agg);
    combine_kernel<<<(N_NODES * 4 + 255) / 256, 256, 0, stream>>>(x, agg, deg, rootT, bias_c, x1, 1, 1);

    // layer 2 (agg was re-zeroed by combine 1)
    conv_kernel<<<(N_EDGES + 127) / 128, 256, 0, stream>>>(x1, ea, w_e1, b_e1, Bz, esrc, edst, agg);
    combine_kernel<<<(N_NODES * 4 + 255) / 256, 256, 0, stream>>>(x1, agg, deg, rootT, bias_c, x2, 0, 0);

    // fused Set2Set (3 iterations) + head: one block per graph
    s2s_kernel<<<N_GRAPHS, 64, 0, stream>>>(x2, offs, w_ih, w_hh, b_ih, b_hh,
                                            w_fc2, b_fc2, w_fc3, b_fc3, out);
}

// Round 16
// 287.211 us; speedup vs baseline: 1.1246x; 1.0288x over previous
//
#include <hip/hip_runtime.h>
#include <math.h>

#define N_NODES 50000
#define N_EDGES 200000
#define N_GRAPHS 1024
#define DIM 24
#define EF 8
#define EH 128
#define DD 576   // 24*24
#define HSTR 136 // hs row stride in f16: 128 + 8 pad (breaks stage-A/read bank conflicts)

typedef __attribute__((ext_vector_type(8))) _Float16 f16x8;
typedef __attribute__((ext_vector_type(4))) _Float16 f16x4;
typedef __attribute__((ext_vector_type(2))) _Float16 f16x2;
typedef __attribute__((ext_vector_type(4))) float float4e;
typedef _Float16 f16;

// ---------- helpers ----------
static __device__ __forceinline__ float sigm(float x) { return 1.0f / (1.0f + expf(-x)); }

// asm b-fragment loads: cannot be sunk/elided by the compiler (VGPR=64 across
// r12-r15 proved the C-level "pipeline" was being collapsed to just-in-time
// loads, exposing ~300cyc L2 latency per K-step).
// voff = lane*16 + step*2048 (32-bit), saddr = Bz. b1 is +1024B -> imm offset.
#define B_LOAD0(dst, voff) \
    asm volatile("global_load_dwordx4 %0, %1, %2" : "=v"(dst) : "v"(voff), "s"(Bz))
#define B_LOAD1(dst, voff) \
    asm volatile("global_load_dwordx4 %0, %1, %2 offset:1024" : "=v"(dst) : "v"(voff), "s"(Bz))
// counted wait; "+v" ties the consumed frags into the asm's dataflow so the
// MFMAs cannot be scheduled above it (rule-18 analog, no sched_barrier needed)
#define B_WAIT(n, r0, r1) \
    asm volatile("s_waitcnt vmcnt(" #n ")" : "+v"(r0), "+v"(r1))

// ---------- prep: deg + Bz swizzle + rootT + graph-offset table, one dispatch ----------
// blocks 0..781: deg; 782..1169: Bz; 1170..1172: rootT; 1173..1368: offs.
// Bz layout: [p 97][nt 2][lane 64][kk 8] f16; lane = quad*16+l16,
// element = B[k32=quad*8+kk][n=nt*16+l16] (n>=24 -> 0). p = si*24+i covers
// k-window si*32..+32 of x-feature i; p=96 = bias block. 198,656 B, L2-resident.
__global__ __launch_bounds__(256) void prep_kernel(
    const int* __restrict__ dst, int* __restrict__ deg,
    const float* __restrict__ w2, const float* __restrict__ b2,
    const float* __restrict__ root, const int* __restrict__ batch,
    f16* __restrict__ Bz, float* __restrict__ rootT, int* __restrict__ offs)
{
    const int b = blockIdx.x, t = threadIdx.x;
    if (b < 782) {
        int i = b * 256 + t;
        if (i < N_EDGES) atomicAdd(&deg[dst[i]], 1);
        return;
    }
    if (b < 1170) {
        int idx = (b - 782) * 256 + t;
        if (idx >= 97 * 2 * 64 * 8) return;
        int kk = idx & 7, lane = (idx >> 3) & 63, nt = (idx >> 9) & 1, p = idx >> 10;
        int q = lane >> 4, l16 = lane & 15, n = nt * 16 + l16;
        float v = 0.0f;
        if (p < 96) {
            int si = p / 24, i = p % 24;
            int k = si * 32 + q * 8 + kk;
            if (n < 24) v = w2[(size_t)k * DD + i * 24 + n];
        } else {
            int i2 = q * 8 + kk;
            if (i2 < 24 && n < 24) v = b2[i2 * 24 + n];
        }
        Bz[idx] = (f16)v;
        return;
    }
    if (b < 1173) {
        int idx = (b - 1170) * 256 + t;   // rootT[o][i] = root[i][o]
        if (idx < DD) {
            int i = idx / 24, o = idx % 24;
            rootT[o * 24 + i] = root[idx];
        }
        return;
    }
    // ---- graph offsets from sorted batch ----
    int n = (b - 1173) * 256 + t;
    if (n >= N_NODES) return;
    int b0 = batch[n];
    if (n == 0)
        for (int g = 0; g <= b0; ++g) offs[g] = 0;
    int b1 = (n + 1 < N_NODES) ? batch[n + 1] : N_GRAPHS;
    for (int g = b0 + 1; g <= b1; ++g) offs[g] = n + 1;
}

// ---------- fused NNConv: h-MLP + per-edge matvec as one z-GEMM, no W ----------
// r12 geometry (FROZEN: block 256 / 4 waves / 128 edges / M=32 / raw in-loop
// barriers). Round-16 change: b-fragment pipeline realized via inline-asm
// global_load_dwordx4 + counted vmcnt (see macros above). Steady state keeps
// 8 loads in flight (4 steps x 2); waits: vmcnt(6) for p<=93, then 4/2/0
// drain. Prologue's 8 loads complete under stage A + the one full barrier.
__global__ __launch_bounds__(256, 4) void conv_kernel(
    const float* __restrict__ x, const float* __restrict__ ea,
    const float* __restrict__ w1, const float* __restrict__ b1,
    const f16* __restrict__ Bz,
    const int* __restrict__ src, const int* __restrict__ dst,
    float* __restrict__ agg)
{
    __shared__ f16 hs[128 * HSTR];   // 34,816 B -> 4 blocks/CU

    const int t  = threadIdx.x;
    const int e0 = blockIdx.x * 128;

    const int lane = t & 63;
    const int wave = t >> 6;             // wave owns edges e0+wave*32 .. +32
    const int l16  = lane & 15;          // A row (edge) / B col / C col
    const int quad = lane >> 4;          // k sub-block / C row group
    const int ebase = e0 + wave * 32;
    const unsigned vbase = (unsigned)lane * 16;   // byte offset of this lane's frag

    // ---- prime depth-4 b-frag pipeline: 8 asm loads, slots 0..3 ----
    f16x8 pb0[4], pb1[4];
    {
        unsigned v0 = vbase;
        B_LOAD0(pb0[0], v0); B_LOAD1(pb1[0], v0);
        unsigned v1 = vbase + 2048;
        B_LOAD0(pb0[1], v1); B_LOAD1(pb1[1], v1);
        unsigned v2 = vbase + 4096;
        B_LOAD0(pb0[2], v2); B_LOAD1(pb1[2], v2);
        unsigned v3 = vbase + 6144;
        B_LOAD0(pb0[3], v3); B_LOAD1(pb1[3], v3);
    }

    // ---- x rows for both m-tiles -> f16 registers (L1 dedups across quads) ----
    f16x2 xa[12], xb[12];
    {
        int ega = ebase + l16;      if (ega >= N_EDGES) ega = N_EDGES - 1;
        int egb = ebase + 16 + l16; if (egb >= N_EDGES) egb = N_EDGES - 1;
        const float* xra = x + (size_t)src[ega] * DIM;
        const float* xrb = x + (size_t)src[egb] * DIM;
        #pragma unroll
        for (int j4 = 0; j4 < 6; ++j4) {
            float4 va = *(const float4*)(xra + j4 * 4);
            float4 vb = *(const float4*)(xrb + j4 * 4);
            xa[j4 * 2]     = (f16x2){(f16)va.x, (f16)va.y};
            xa[j4 * 2 + 1] = (f16x2){(f16)va.z, (f16)va.w};
            xb[j4 * 2]     = (f16x2){(f16)vb.x, (f16)vb.y};
            xb[j4 * 2 + 1] = (f16x2){(f16)vb.z, (f16)vb.w};
        }
    }

    // ---- stage A: h = relu(ea@w1+b1) -> hs[edge][k]; thread = 4-k-slice x 16 edges ----
    {
        const int s5 = t & 31;           // k = s5*4 .. s5*4+3
        const int eb = (t >> 5) * 16;    // 16 edges starting here
        float wv[EF][4];
        #pragma unroll
        for (int j = 0; j < EF; ++j) {
            float4 v = *(const float4*)(w1 + j * EH + s5 * 4);
            wv[j][0] = v.x; wv[j][1] = v.y; wv[j][2] = v.z; wv[j][3] = v.w;
        }
        float4 bv = *(const float4*)(b1 + s5 * 4);
        const float bvv[4] = {bv.x, bv.y, bv.z, bv.w};
        #pragma unroll
        for (int e = 0; e < 16; ++e) {
            int eg = e0 + eb + e; if (eg >= N_EDGES) eg = N_EDGES - 1;  // clamp tail
            const float* ear = ea + (size_t)eg * EF;
            float4 a0 = *(const float4*)ear;
            float4 a1 = *(const float4*)(ear + 4);
            const float av[EF] = {a0.x, a0.y, a0.z, a0.w, a1.x, a1.y, a1.z, a1.w};
            float r[4] = {bvv[0], bvv[1], bvv[2], bvv[3]};
            #pragma unroll
            for (int j = 0; j < EF; ++j)
                #pragma unroll
                for (int c = 0; c < 4; ++c)
                    r[c] = fmaf(av[j], wv[j][c], r[c]);
            f16x4 hq = { (f16)fmaxf(r[0], 0.0f), (f16)fmaxf(r[1], 0.0f),
                         (f16)fmaxf(r[2], 0.0f), (f16)fmaxf(r[3], 0.0f) };
            *(f16x4*)&hs[(eb + e) * HSTR + s5 * 4] = hq;
        }
    }

    __syncthreads();   // correctness: hs visible; drains vmcnt(0) -> all 8 prologue loads valid

    float4e a00 = {0.f,0.f,0.f,0.f}, a01 = {0.f,0.f,0.f,0.f};
    float4e a10 = {0.f,0.f,0.f,0.f}, a11 = {0.f,0.f,0.f,0.f};

    #pragma unroll
    for (int si = 0; si < 4; ++si) {
        union { f16x8 v; f16x2 p[4]; } h0u, h1u;
        h0u.v = *(const f16x8*)&hs[(wave * 32 + l16) * HSTR + si * 32 + quad * 8];
        h1u.v = *(const f16x8*)&hs[(wave * 32 + 16 + l16) * HSTR + si * 32 + quad * 8];
        #pragma unroll
        for (int i = 0; i < 24; ++i) {
            const int p = si * 24 + i;          // compile-time
            // wait for this step's fragments (issued 4 steps ago / prologue)
            if (p <= 93)      { B_WAIT(6, pb0[p & 3], pb1[p & 3]); }
            else if (p == 94) { B_WAIT(4, pb0[p & 3], pb1[p & 3]); }
            else              { B_WAIT(2, pb0[p & 3], pb1[p & 3]); }
            f16x8 b0 = pb0[p & 3], b1v = pb1[p & 3];

            f16 xea = (i & 1) ? xa[i >> 1][1] : xa[i >> 1][0];
            f16 xeb = (i & 1) ? xb[i >> 1][1] : xb[i >> 1][0];
            f16x2 xa2 = {xea, xea}, xb2 = {xeb, xeb};
            union { f16x8 v; f16x2 p[4]; } a0u, a1u;
            #pragma unroll
            for (int j = 0; j < 4; ++j) {
                a0u.p[j] = h0u.p[j] * xa2;      // v_pk_mul_f16
                a1u.p[j] = h1u.p[j] * xb2;
            }
            a00 = __builtin_amdgcn_mfma_f32_16x16x32_f16(a0u.v, b0,  a00, 0, 0, 0);
            a10 = __builtin_amdgcn_mfma_f32_16x16x32_f16(a1u.v, b0,  a10, 0, 0, 0);
            a01 = __builtin_amdgcn_mfma_f32_16x16x32_f16(a0u.v, b1v, a01, 0, 0, 0);
            a11 = __builtin_amdgcn_mfma_f32_16x16x32_f16(a1u.v, b1v, a11, 0, 0, 0);

            // refill freed slot: loads for step p+4 (cannot be sunk: asm volatile)
            if (p + 4 <= 96) {
                unsigned voff = vbase + (unsigned)((p + 4) * 2048);
                B_LOAD0(pb0[p & 3], voff);
                B_LOAD1(pb1[p & 3], voff);
            }
            // lockstep hint only (no data dep): RAW barrier, no vmcnt drain.
            if ((p % 12) == 11) __builtin_amdgcn_s_barrier();
        }
    }

    // ---- bias step (p = 96): A = x row slices, B = b2 reshaped; frags in slot 0 ----
    {
        asm volatile("s_waitcnt vmcnt(0)" : "+v"(pb0[0]), "+v"(pb1[0]));
        union { f16x8 v; f16x2 p[4]; } a0u, a1u;
        f16x2 z2 = {(f16)0.f, (f16)0.f};
        if (quad == 0)      { a0u.p[0]=xa[0]; a0u.p[1]=xa[1]; a0u.p[2]=xa[2];  a0u.p[3]=xa[3];
                              a1u.p[0]=xb[0]; a1u.p[1]=xb[1]; a1u.p[2]=xb[2];  a1u.p[3]=xb[3];  }
        else if (quad == 1) { a0u.p[0]=xa[4]; a0u.p[1]=xa[5]; a0u.p[2]=xa[6];  a0u.p[3]=xa[7];
                              a1u.p[0]=xb[4]; a1u.p[1]=xb[5]; a1u.p[2]=xb[6];  a1u.p[3]=xb[7];  }
        else if (quad == 2) { a0u.p[0]=xa[8]; a0u.p[1]=xa[9]; a0u.p[2]=xa[10]; a0u.p[3]=xa[11];
                              a1u.p[0]=xb[8]; a1u.p[1]=xb[9]; a1u.p[2]=xb[10]; a1u.p[3]=xb[11]; }
        else                { a0u.p[0]=z2; a0u.p[1]=z2; a0u.p[2]=z2; a0u.p[3]=z2;
                              a1u.p[0]=z2; a1u.p[1]=z2; a1u.p[2]=z2; a1u.p[3]=z2; }
        a00 = __builtin_amdgcn_mfma_f32_16x16x32_f16(a0u.v, pb0[0], a00, 0, 0, 0);
        a10 = __builtin_amdgcn_mfma_f32_16x16x32_f16(a1u.v, pb0[0], a10, 0, 0, 0);
        a01 = __builtin_amdgcn_mfma_f32_16x16x32_f16(a0u.v, pb1[0], a01, 0, 0, 0);
        a11 = __builtin_amdgcn_mfma_f32_16x16x32_f16(a1u.v, pb1[0], a11, 0, 0, 0);
    }

    // ---- scatter: C row = quad*4+r (edge), col = l16 (+16) = o ----
    #pragma unroll
    for (int r = 0; r < 4; ++r) {
        int er = ebase + quad * 4 + r;
        if (er < N_EDGES) {
            int d = dst[er];
            atomicAdd(&agg[(size_t)d * DIM + l16], a00[r]);
            if (l16 < 8) atomicAdd(&agg[(size_t)d * DIM + 16 + l16], a01[r]);
        }
        int er2 = ebase + 16 + quad * 4 + r;
        if (er2 < N_EDGES) {
            int d = dst[er2];
            atomicAdd(&agg[(size_t)d * DIM + l16], a10[r]);
            if (l16 < 8) atomicAdd(&agg[(size_t)d * DIM + 16 + l16], a11[r]);
        }
    }
}

// ---------- combine: x_out = [relu](agg/max(deg,1) + x_in@rootT^T + bias) ----------
// Vectorized: thread = (node, quarter of 6 outputs); float4 x/rootT loads.
// zero_agg=1: write agg=0 after reading (folds the inter-layer memset).
__global__ __launch_bounds__(256) void combine_kernel(
    const float* __restrict__ x_in, float* __restrict__ agg,
    const int* __restrict__ deg, const float* __restrict__ rootT,
    const float* __restrict__ bias, float* __restrict__ x_out,
    int do_relu, int zero_agg)
{
    int gid = blockIdx.x * 256 + threadIdx.x;
    int v = gid >> 2, q = gid & 3;
    if (v >= N_NODES) return;
    const int o0 = q * 6;

    float xv[24];
    const float4* xr = (const float4*)(x_in + (size_t)v * DIM);
    #pragma unroll
    for (int j = 0; j < 6; ++j) *(float4*)&xv[j * 4] = xr[j];

    int dg = deg[v];
    float dinv = 1.0f / (dg > 0 ? (float)dg : 1.0f);
    float* aggr = agg + (size_t)v * DIM + o0;

    float r[6];
    #pragma unroll
    for (int u = 0; u < 6; ++u) {
        int o = o0 + u;
        float a = aggr[u] * dinv + bias[o];
        const float4* rt = (const float4*)(rootT + o * 24);
        #pragma unroll
        for (int j = 0; j < 6; ++j) {
            float4 w = rt[j];
            a = fmaf(xv[j*4+0], w.x, a); a = fmaf(xv[j*4+1], w.y, a);
            a = fmaf(xv[j*4+2], w.z, a); a = fmaf(xv[j*4+3], w.w, a);
        }
        r[u] = do_relu ? fmaxf(a, 0.0f) : a;
    }
    if (zero_agg) {
        #pragma unroll
        for (int u = 0; u < 6; ++u) aggr[u] = 0.0f;
    }
    float* xo = x_out + (size_t)v * DIM + o0;
    #pragma unroll
    for (int u = 0; u < 6; ++u) xo[u] = r[u];
}

// ---------- fused Set2Set (3x LSTM+attention) + head: one block per graph ----------
__global__ __launch_bounds__(64) void s2s_kernel(
    const float* __restrict__ x, const int* __restrict__ offs,
    const float* __restrict__ w_ih, const float* __restrict__ w_hh,
    const float* __restrict__ b_ih, const float* __restrict__ b_hh,
    const float* __restrict__ w_fc2, const float* __restrict__ b_fc2,
    const float* __restrict__ w_fc3, const float* __restrict__ b_fc3,
    float* __restrict__ out)
{
    const int g = blockIdx.x;
    const int t = threadIdx.x;     // 64 = 1 wave
    __shared__ float qs[48];       // q_star = [q | r]
    __shared__ float hh[24], cc[24], gates[96], zl[8];

    const int lo = offs[g], hi = offs[g + 1];

    if (t < 48) qs[t] = 0.0f;
    if (t < 24) { hh[t] = 0.0f; cc[t] = 0.0f; }
    __syncthreads();

    for (int it = 0; it < 3; ++it) {
        // ---- LSTM gates (float4 weight loads) ----
        for (int rr = t; rr < 96; rr += 64) {
            float a = b_ih[rr] + b_hh[rr];
            const float* wi = w_ih + (size_t)rr * 48;
            const float* wh = w_hh + (size_t)rr * 24;
            #pragma unroll
            for (int j4 = 0; j4 < 12; ++j4) {
                float4 w = *(const float4*)(wi + j4 * 4);
                a = fmaf(qs[j4*4+0], w.x, a); a = fmaf(qs[j4*4+1], w.y, a);
                a = fmaf(qs[j4*4+2], w.z, a); a = fmaf(qs[j4*4+3], w.w, a);
            }
            #pragma unroll
            for (int j4 = 0; j4 < 6; ++j4) {
                float4 w = *(const float4*)(wh + j4 * 4);
                a = fmaf(hh[j4*4+0], w.x, a); a = fmaf(hh[j4*4+1], w.y, a);
                a = fmaf(hh[j4*4+2], w.z, a); a = fmaf(hh[j4*4+3], w.w, a);
            }
            gates[rr] = a;
        }
        __syncthreads();
        if (t < 24) {
            float c = sigm(gates[24 + t]) * cc[t] + sigm(gates[t]) * tanhf(gates[48 + t]);
            cc[t] = c;
            float h = sigm(gates[72 + t]) * tanhf(c);
            hh[t] = h;
            qs[t] = h;               // q part of q_star
        }
        __syncthreads();

        // ---- attention: single-pass online softmax over this graph's nodes ----
        float m_l = -INFINITY, s_l = 0.0f;
        float r_l[24];
        #pragma unroll
        for (int d = 0; d < 24; ++d) r_l[d] = 0.0f;
        for (int n = lo + t; n < hi; n += 64) {
            float xv[24];
            #pragma unroll
            for (int j = 0; j < 6; ++j)
                *(float4*)&xv[j * 4] = ((const float4*)(x + (size_t)n * DIM))[j];
            float e = 0.0f;
            #pragma unroll
            for (int d = 0; d < 24; ++d) e = fmaf(xv[d], qs[d], e);
            if (e > m_l) {
                float sc = expf(m_l - e);   // exp(-inf)=0 on first node: zeros stale acc
                #pragma unroll
                for (int d = 0; d < 24; ++d) r_l[d] *= sc;
                s_l *= sc;
                m_l = e;
            }
            float w = expf(e - m_l);
            s_l += w;
            #pragma unroll
            for (int d = 0; d < 24; ++d) r_l[d] = fmaf(w, xv[d], r_l[d]);
        }
        // cross-lane merge: global max, then rescale partial sums
        float m = m_l;
        #pragma unroll
        for (int off = 32; off; off >>= 1) m = fmaxf(m, __shfl_xor(m, off));
        float fac = (m_l == -INFINITY) ? 0.0f : expf(m_l - m);
        float s = s_l * fac;
        #pragma unroll
        for (int off = 32; off; off >>= 1) s += __shfl_xor(s, off);
        float denom = fmaxf(s, 1e-16f);
        #pragma unroll
        for (int d = 0; d < 24; ++d) {
            float rv = r_l[d] * fac;
            #pragma unroll
            for (int off = 32; off; off >>= 1) rv += __shfl_xor(rv, off);
            if (t == d) qs[24 + d] = rv / denom;   // compile-time d: no scratch array
        }
        __syncthreads();
    }

    // ---- head: out = relu(q_star@w_fc2+b2)@w_fc3+b3 ----
    if (t < 8) {
        float a = b_fc2[t];
        #pragma unroll
        for (int j = 0; j < 48; ++j) a = fmaf(qs[j], w_fc2[j * 8 + t], a);
        zl[t] = fmaxf(a, 0.0f);
    }
    __syncthreads();
    if (t < 2) {
        float a = b_fc3[t];
        #pragma unroll
        for (int k = 0; k < 8; ++k) a = fmaf(zl[k], w_fc3[k * 2 + t], a);
        out[(size_t)g * 2 + t] = a;
    }
}

extern "C" void kernel_launch(void* const* d_in, const int* in_sizes, int n_in,
                              void* d_out, int out_size, void* d_ws, size_t ws_size,
                              hipStream_t stream) {
    const float* x      = (const float*)d_in[0];
    const float* ea     = (const float*)d_in[1];
    const float* w_e1   = (const float*)d_in[2];
    const float* b_e1   = (const float*)d_in[3];
    const float* w_e2   = (const float*)d_in[4];
    const float* b_e2   = (const float*)d_in[5];
    const float* root   = (const float*)d_in[6];
    const float* bias_c = (const float*)d_in[7];
    const float* w_ih   = (const float*)d_in[8];
    const float* w_hh   = (const float*)d_in[9];
    const float* b_ih   = (const float*)d_in[10];
    const float* b_hh   = (const float*)d_in[11];
    const float* w_fc2  = (const float*)d_in[12];
    const float* b_fc2  = (const float*)d_in[13];
    const float* w_fc3  = (const float*)d_in[14];
    const float* b_fc3  = (const float*)d_in[15];
    const int*   eidx   = (const int*)d_in[16];
    const int*   batch  = (const int*)d_in[17];
    const int* esrc = eidx;
    const int* edst = eidx + N_EDGES;
    float* out = (float*)d_out;

    // workspace layout (bytes)
    char* ws = (char*)d_ws;
    float* agg   = (float*)(ws);                  // 4,800,000
    int*   deg   = (int*)  (ws + 4800000);        //   200,000
    float* x1    = (float*)(ws + 5789824);        // 4,800,000
    float* x2    = (float*)(ws + 10589824);       // 4,800,000
    f16*   Bz    = (f16*)  (ws + 15389824);       //   198,656 swizzled f16 w2+b2
    float* rootT = (float*)(ws + 15588480);       //     2,304 transposed root
    int*   offs  = (int*)  (ws + 15590784);       //     4,100 graph offsets [1025]

    // zero: agg + deg
    hipMemsetAsync(ws, 0, 5000000, stream);

    // deg + Bz + rootT + offs in one dispatch
    prep_kernel<<<1369, 256, 0, stream>>>(edst, deg, w_e2, b_e2, root, batch, Bz, rootT, offs);

    // layer 1 (fused edge-MLP + message + scatter; no W materialization)
    conv_kernel<<<(N_EDGES + 127) / 128, 256, 0, stream>>>(x, ea, w_e1, b_e1, Bz, esrc, edst, agg);
    combine_kernel<<<(N_NODES * 4 + 255) / 256, 256, 0, stream>>>(x, agg, deg, rootT, bias_c, x1, 1, 1);

    // layer 2 (agg was re-zeroed by combine 1)
    conv_kernel<<<(N_EDGES + 127) / 128, 256, 0, stream>>>(x1, ea, w_e1, b_e1, Bz, esrc, edst, agg);
    combine_kernel<<<(N_NODES * 4 + 255) / 256, 256, 0, stream>>>(x1, agg, deg, rootT, bias_c, x2, 0, 0);

    // fused Set2Set (3 iterations) + head: one block per graph
    s2s_kernel<<<N_GRAPHS, 64, 0, stream>>>(x2, offs, w_ih, w_hh, b_ih, b_hh,
                                            w_fc2, b_fc2, w_fc3, b_fc3, out);
}

// Round 17
// 285.218 us; speedup vs baseline: 1.1325x; 1.0070x over previous
//
#include <hip/hip_runtime.h>
#include <math.h>

#define N_NODES 50000
#define N_EDGES 200000
#define N_GRAPHS 1024
#define DIM 24
#define EF 8
#define EH 128
#define DD 576   // 24*24
#define HSTR 136 // hs row stride in f16: 128 + 8 pad (breaks stage-A/read bank conflicts)

typedef __attribute__((ext_vector_type(8))) _Float16 f16x8;
typedef __attribute__((ext_vector_type(4))) _Float16 f16x4;
typedef __attribute__((ext_vector_type(2))) _Float16 f16x2;
typedef __attribute__((ext_vector_type(4))) float float4e;
typedef _Float16 f16;

// ---------- helpers ----------
static __device__ __forceinline__ float sigm(float x) { return 1.0f / (1.0f + expf(-x)); }

// asm b-fragment loads: cannot be sunk/elided by the compiler (VGPR=64 across
// r12-r15 proved the C-level "pipeline" was being collapsed to just-in-time
// loads, exposing ~300cyc L2 latency per K-step). r16: -6% conv time.
#define B_LOAD0(dst, voff) \
    asm volatile("global_load_dwordx4 %0, %1, %2" : "=v"(dst) : "v"(voff), "s"(Bz))
#define B_LOAD1(dst, voff) \
    asm volatile("global_load_dwordx4 %0, %1, %2 offset:1024" : "=v"(dst) : "v"(voff), "s"(Bz))
#define B_WAIT(n, r0, r1) \
    asm volatile("s_waitcnt vmcnt(" #n ")" : "+v"(r0), "+v"(r1))

// ---------- prep: deg + Bz swizzle + rootT + graph-offset table, one dispatch ----------
__global__ __launch_bounds__(256) void prep_kernel(
    const int* __restrict__ dst, int* __restrict__ deg,
    const float* __restrict__ w2, const float* __restrict__ b2,
    const float* __restrict__ root, const int* __restrict__ batch,
    f16* __restrict__ Bz, float* __restrict__ rootT, int* __restrict__ offs)
{
    const int b = blockIdx.x, t = threadIdx.x;
    if (b < 782) {
        int i = b * 256 + t;
        if (i < N_EDGES) atomicAdd(&deg[dst[i]], 1);
        return;
    }
    if (b < 1170) {
        int idx = (b - 782) * 256 + t;
        if (idx >= 97 * 2 * 64 * 8) return;
        int kk = idx & 7, lane = (idx >> 3) & 63, nt = (idx >> 9) & 1, p = idx >> 10;
        int q = lane >> 4, l16 = lane & 15, n = nt * 16 + l16;
        float v = 0.0f;
        if (p < 96) {
            int si = p / 24, i = p % 24;
            int k = si * 32 + q * 8 + kk;
            if (n < 24) v = w2[(size_t)k * DD + i * 24 + n];
        } else {
            int i2 = q * 8 + kk;
            if (i2 < 24 && n < 24) v = b2[i2 * 24 + n];
        }
        Bz[idx] = (f16)v;
        return;
    }
    if (b < 1173) {
        int idx = (b - 1170) * 256 + t;   // rootT[o][i] = root[i][o]
        if (idx < DD) {
            int i = idx / 24, o = idx % 24;
            rootT[o * 24 + i] = root[idx];
        }
        return;
    }
    // ---- graph offsets from sorted batch ----
    int n = (b - 1173) * 256 + t;
    if (n >= N_NODES) return;
    int b0 = batch[n];
    if (n == 0)
        for (int g = 0; g <= b0; ++g) offs[g] = 0;
    int b1 = (n + 1 < N_NODES) ? batch[n + 1] : N_GRAPHS;
    for (int g = b0 + 1; g <= b1; ++g) offs[g] = n + 1;
}

// ---------- fused NNConv: h-MLP + per-edge matvec as one z-GEMM, no W ----------
// FROZEN r16 form (71.0us, best): r12 geometry + inline-asm b-loads with
// counted vmcnt. Steady state 8 loads in flight; waits 6/4/2/0.
__global__ __launch_bounds__(256, 4) void conv_kernel(
    const float* __restrict__ x, const float* __restrict__ ea,
    const float* __restrict__ w1, const float* __restrict__ b1,
    const f16* __restrict__ Bz,
    const int* __restrict__ src, const int* __restrict__ dst,
    float* __restrict__ agg)
{
    __shared__ f16 hs[128 * HSTR];   // 34,816 B -> 4 blocks/CU

    const int t  = threadIdx.x;
    const int e0 = blockIdx.x * 128;

    const int lane = t & 63;
    const int wave = t >> 6;             // wave owns edges e0+wave*32 .. +32
    const int l16  = lane & 15;          // A row (edge) / B col / C col
    const int quad = lane >> 4;          // k sub-block / C row group
    const int ebase = e0 + wave * 32;
    const unsigned vbase = (unsigned)lane * 16;   // byte offset of this lane's frag

    // ---- prime depth-4 b-frag pipeline: 8 asm loads, slots 0..3 ----
    f16x8 pb0[4], pb1[4];
    {
        unsigned v0 = vbase;
        B_LOAD0(pb0[0], v0); B_LOAD1(pb1[0], v0);
        unsigned v1 = vbase + 2048;
        B_LOAD0(pb0[1], v1); B_LOAD1(pb1[1], v1);
        unsigned v2 = vbase + 4096;
        B_LOAD0(pb0[2], v2); B_LOAD1(pb1[2], v2);
        unsigned v3 = vbase + 6144;
        B_LOAD0(pb0[3], v3); B_LOAD1(pb1[3], v3);
    }

    // ---- x rows for both m-tiles -> f16 registers (L1 dedups across quads) ----
    f16x2 xa[12], xb[12];
    {
        int ega = ebase + l16;      if (ega >= N_EDGES) ega = N_EDGES - 1;
        int egb = ebase + 16 + l16; if (egb >= N_EDGES) egb = N_EDGES - 1;
        const float* xra = x + (size_t)src[ega] * DIM;
        const float* xrb = x + (size_t)src[egb] * DIM;
        #pragma unroll
        for (int j4 = 0; j4 < 6; ++j4) {
            float4 va = *(const float4*)(xra + j4 * 4);
            float4 vb = *(const float4*)(xrb + j4 * 4);
            xa[j4 * 2]     = (f16x2){(f16)va.x, (f16)va.y};
            xa[j4 * 2 + 1] = (f16x2){(f16)va.z, (f16)va.w};
            xb[j4 * 2]     = (f16x2){(f16)vb.x, (f16)vb.y};
            xb[j4 * 2 + 1] = (f16x2){(f16)vb.z, (f16)vb.w};
        }
    }

    // ---- stage A: h = relu(ea@w1+b1) -> hs[edge][k]; thread = 4-k-slice x 16 edges ----
    {
        const int s5 = t & 31;           // k = s5*4 .. s5*4+3
        const int eb = (t >> 5) * 16;    // 16 edges starting here
        float wv[EF][4];
        #pragma unroll
        for (int j = 0; j < EF; ++j) {
            float4 v = *(const float4*)(w1 + j * EH + s5 * 4);
            wv[j][0] = v.x; wv[j][1] = v.y; wv[j][2] = v.z; wv[j][3] = v.w;
        }
        float4 bv = *(const float4*)(b1 + s5 * 4);
        const float bvv[4] = {bv.x, bv.y, bv.z, bv.w};
        #pragma unroll
        for (int e = 0; e < 16; ++e) {
            int eg = e0 + eb + e; if (eg >= N_EDGES) eg = N_EDGES - 1;  // clamp tail
            const float* ear = ea + (size_t)eg * EF;
            float4 a0 = *(const float4*)ear;
            float4 a1 = *(const float4*)(ear + 4);
            const float av[EF] = {a0.x, a0.y, a0.z, a0.w, a1.x, a1.y, a1.z, a1.w};
            float r[4] = {bvv[0], bvv[1], bvv[2], bvv[3]};
            #pragma unroll
            for (int j = 0; j < EF; ++j)
                #pragma unroll
                for (int c = 0; c < 4; ++c)
                    r[c] = fmaf(av[j], wv[j][c], r[c]);
            f16x4 hq = { (f16)fmaxf(r[0], 0.0f), (f16)fmaxf(r[1], 0.0f),
                         (f16)fmaxf(r[2], 0.0f), (f16)fmaxf(r[3], 0.0f) };
            *(f16x4*)&hs[(eb + e) * HSTR + s5 * 4] = hq;
        }
    }

    __syncthreads();   // correctness: hs visible; drains vmcnt(0) -> all 8 prologue loads valid

    float4e a00 = {0.f,0.f,0.f,0.f}, a01 = {0.f,0.f,0.f,0.f};
    float4e a10 = {0.f,0.f,0.f,0.f}, a11 = {0.f,0.f,0.f,0.f};

    #pragma unroll
    for (int si = 0; si < 4; ++si) {
        union { f16x8 v; f16x2 p[4]; } h0u, h1u;
        h0u.v = *(const f16x8*)&hs[(wave * 32 + l16) * HSTR + si * 32 + quad * 8];
        h1u.v = *(const f16x8*)&hs[(wave * 32 + 16 + l16) * HSTR + si * 32 + quad * 8];
        #pragma unroll
        for (int i = 0; i < 24; ++i) {
            const int p = si * 24 + i;          // compile-time
            if (p <= 93)      { B_WAIT(6, pb0[p & 3], pb1[p & 3]); }
            else if (p == 94) { B_WAIT(4, pb0[p & 3], pb1[p & 3]); }
            else              { B_WAIT(2, pb0[p & 3], pb1[p & 3]); }
            f16x8 b0 = pb0[p & 3], b1v = pb1[p & 3];

            f16 xea = (i & 1) ? xa[i >> 1][1] : xa[i >> 1][0];
            f16 xeb = (i & 1) ? xb[i >> 1][1] : xb[i >> 1][0];
            f16x2 xa2 = {xea, xea}, xb2 = {xeb, xeb};
            union { f16x8 v; f16x2 p[4]; } a0u, a1u;
            #pragma unroll
            for (int j = 0; j < 4; ++j) {
                a0u.p[j] = h0u.p[j] * xa2;      // v_pk_mul_f16
                a1u.p[j] = h1u.p[j] * xb2;
            }
            a00 = __builtin_amdgcn_mfma_f32_16x16x32_f16(a0u.v, b0,  a00, 0, 0, 0);
            a10 = __builtin_amdgcn_mfma_f32_16x16x32_f16(a1u.v, b0,  a10, 0, 0, 0);
            a01 = __builtin_amdgcn_mfma_f32_16x16x32_f16(a0u.v, b1v, a01, 0, 0, 0);
            a11 = __builtin_amdgcn_mfma_f32_16x16x32_f16(a1u.v, b1v, a11, 0, 0, 0);

            if (p + 4 <= 96) {
                unsigned voff = vbase + (unsigned)((p + 4) * 2048);
                B_LOAD0(pb0[p & 3], voff);
                B_LOAD1(pb1[p & 3], voff);
            }
            if ((p % 12) == 11) __builtin_amdgcn_s_barrier();
        }
    }

    // ---- bias step (p = 96): A = x row slices, B = b2 reshaped; frags in slot 0 ----
    {
        asm volatile("s_waitcnt vmcnt(0)" : "+v"(pb0[0]), "+v"(pb1[0]));
        union { f16x8 v; f16x2 p[4]; } a0u, a1u;
        f16x2 z2 = {(f16)0.f, (f16)0.f};
        if (quad == 0)      { a0u.p[0]=xa[0]; a0u.p[1]=xa[1]; a0u.p[2]=xa[2];  a0u.p[3]=xa[3];
                              a1u.p[0]=xb[0]; a1u.p[1]=xb[1]; a1u.p[2]=xb[2];  a1u.p[3]=xb[3];  }
        else if (quad == 1) { a0u.p[0]=xa[4]; a0u.p[1]=xa[5]; a0u.p[2]=xa[6];  a0u.p[3]=xa[7];
                              a1u.p[0]=xb[4]; a1u.p[1]=xb[5]; a1u.p[2]=xb[6];  a1u.p[3]=xb[7];  }
        else if (quad == 2) { a0u.p[0]=xa[8]; a0u.p[1]=xa[9]; a0u.p[2]=xa[10]; a0u.p[3]=xa[11];
                              a1u.p[0]=xb[8]; a1u.p[1]=xb[9]; a1u.p[2]=xb[10]; a1u.p[3]=xb[11]; }
        else                { a0u.p[0]=z2; a0u.p[1]=z2; a0u.p[2]=z2; a0u.p[3]=z2;
                              a1u.p[0]=z2; a1u.p[1]=z2; a1u.p[2]=z2; a1u.p[3]=z2; }
        a00 = __builtin_amdgcn_mfma_f32_16x16x32_f16(a0u.v, pb0[0], a00, 0, 0, 0);
        a10 = __builtin_amdgcn_mfma_f32_16x16x32_f16(a1u.v, pb0[0], a10, 0, 0, 0);
        a01 = __builtin_amdgcn_mfma_f32_16x16x32_f16(a0u.v, pb1[0], a01, 0, 0, 0);
        a11 = __builtin_amdgcn_mfma_f32_16x16x32_f16(a1u.v, pb1[0], a11, 0, 0, 0);
    }

    // ---- scatter: C row = quad*4+r (edge), col = l16 (+16) = o ----
    #pragma unroll
    for (int r = 0; r < 4; ++r) {
        int er = ebase + quad * 4 + r;
        if (er < N_EDGES) {
            int d = dst[er];
            atomicAdd(&agg[(size_t)d * DIM + l16], a00[r]);
            if (l16 < 8) atomicAdd(&agg[(size_t)d * DIM + 16 + l16], a01[r]);
        }
        int er2 = ebase + 16 + quad * 4 + r;
        if (er2 < N_EDGES) {
            int d = dst[er2];
            atomicAdd(&agg[(size_t)d * DIM + l16], a10[r]);
            if (l16 < 8) atomicAdd(&agg[(size_t)d * DIM + 16 + l16], a11[r]);
        }
    }
}

// ---------- combine: x_out = [relu](agg/max(deg,1) + x_in@rootT^T + bias) ----------
__global__ __launch_bounds__(256) void combine_kernel(
    const float* __restrict__ x_in, float* __restrict__ agg,
    const int* __restrict__ deg, const float* __restrict__ rootT,
    const float* __restrict__ bias, float* __restrict__ x_out,
    int do_relu, int zero_agg)
{
    int gid = blockIdx.x * 256 + threadIdx.x;
    int v = gid >> 2, q = gid & 3;
    if (v >= N_NODES) return;
    const int o0 = q * 6;

    float xv[24];
    const float4* xr = (const float4*)(x_in + (size_t)v * DIM);
    #pragma unroll
    for (int j = 0; j < 6; ++j) *(float4*)&xv[j * 4] = xr[j];

    int dg = deg[v];
    float dinv = 1.0f / (dg > 0 ? (float)dg : 1.0f);
    float* aggr = agg + (size_t)v * DIM + o0;

    float r[6];
    #pragma unroll
    for (int u = 0; u < 6; ++u) {
        int o = o0 + u;
        float a = aggr[u] * dinv + bias[o];
        const float4* rt = (const float4*)(rootT + o * 24);
        #pragma unroll
        for (int j = 0; j < 6; ++j) {
            float4 w = rt[j];
            a = fmaf(xv[j*4+0], w.x, a); a = fmaf(xv[j*4+1], w.y, a);
            a = fmaf(xv[j*4+2], w.z, a); a = fmaf(xv[j*4+3], w.w, a);
        }
        r[u] = do_relu ? fmaxf(a, 0.0f) : a;
    }
    if (zero_agg) {
        #pragma unroll
        for (int u = 0; u < 6; ++u) aggr[u] = 0.0f;
    }
    float* xo = x_out + (size_t)v * DIM + o0;
    #pragma unroll
    for (int u = 0; u < 6; ++u) xo[u] = r[u];
}

// ---------- fused Set2Set (3x LSTM+attention) + head: one block (4 waves) per graph ----------
// Round-17 change: block 64 -> 256 (4 waves). s2s was 1 wave/block = 4 waves/CU
// (latency floor). Attention scan strides 256 with per-wave online-softmax
// state; cross-wave merge via LDS (wm/wsum/wr) with max-shift algebra.
// Empty-wave (-inf) and empty-graph cases guarded to match ref (e_max -> 0).
__global__ __launch_bounds__(256) void s2s_kernel(
    const float* __restrict__ x, const int* __restrict__ offs,
    const float* __restrict__ w_ih, const float* __restrict__ w_hh,
    const float* __restrict__ b_ih, const float* __restrict__ b_hh,
    const float* __restrict__ w_fc2, const float* __restrict__ b_fc2,
    const float* __restrict__ w_fc3, const float* __restrict__ b_fc3,
    float* __restrict__ out)
{
    const int g = blockIdx.x;
    const int t = threadIdx.x;     // 256 = 4 waves
    const int lane = t & 63, w = t >> 6;
    __shared__ float qs[48];       // q_star = [q | r]
    __shared__ float hh[24], cc[24], gates[96], zl[8];
    __shared__ float wm[4], wsum[4], wr[4][24];

    const int lo = offs[g], hi = offs[g + 1];

    if (t < 48) qs[t] = 0.0f;
    if (t < 24) { hh[t] = 0.0f; cc[t] = 0.0f; }
    __syncthreads();

    for (int it = 0; it < 3; ++it) {
        // ---- LSTM gates: one row per thread (t<96), float4 weight loads ----
        if (t < 96) {
            float a = b_ih[t] + b_hh[t];
            const float* wi = w_ih + (size_t)t * 48;
            const float* wh = w_hh + (size_t)t * 24;
            #pragma unroll
            for (int j4 = 0; j4 < 12; ++j4) {
                float4 wv = *(const float4*)(wi + j4 * 4);
                a = fmaf(qs[j4*4+0], wv.x, a); a = fmaf(qs[j4*4+1], wv.y, a);
                a = fmaf(qs[j4*4+2], wv.z, a); a = fmaf(qs[j4*4+3], wv.w, a);
            }
            #pragma unroll
            for (int j4 = 0; j4 < 6; ++j4) {
                float4 wv = *(const float4*)(wh + j4 * 4);
                a = fmaf(hh[j4*4+0], wv.x, a); a = fmaf(hh[j4*4+1], wv.y, a);
                a = fmaf(hh[j4*4+2], wv.z, a); a = fmaf(hh[j4*4+3], wv.w, a);
            }
            gates[t] = a;
        }
        __syncthreads();
        if (t < 24) {
            float c = sigm(gates[24 + t]) * cc[t] + sigm(gates[t]) * tanhf(gates[48 + t]);
            cc[t] = c;
            float h = sigm(gates[72 + t]) * tanhf(c);
            hh[t] = h;
            qs[t] = h;               // q part of q_star
        }
        __syncthreads();

        // ---- attention: online softmax, 256-thread scan ----
        float m_l = -INFINITY, s_l = 0.0f;
        float r_l[24];
        #pragma unroll
        for (int d = 0; d < 24; ++d) r_l[d] = 0.0f;
        for (int n = lo + t; n < hi; n += 256) {
            float xv[24];
            #pragma unroll
            for (int j = 0; j < 6; ++j)
                *(float4*)&xv[j * 4] = ((const float4*)(x + (size_t)n * DIM))[j];
            float e = 0.0f;
            #pragma unroll
            for (int d = 0; d < 24; ++d) e = fmaf(xv[d], qs[d], e);
            if (e > m_l) {
                float sc = expf(m_l - e);   // exp(-inf)=0 on first node: zeros stale acc
                #pragma unroll
                for (int d = 0; d < 24; ++d) r_l[d] *= sc;
                s_l *= sc;
                m_l = e;
            }
            float wgt = expf(e - m_l);
            s_l += wgt;
            #pragma unroll
            for (int d = 0; d < 24; ++d) r_l[d] = fmaf(wgt, xv[d], r_l[d]);
        }
        // intra-wave merge (64 lanes)
        float m = m_l;
        #pragma unroll
        for (int off = 32; off; off >>= 1) m = fmaxf(m, __shfl_xor(m, off));
        float fac = (m_l == -INFINITY) ? 0.0f : expf(m_l - m);
        float s = s_l * fac;
        #pragma unroll
        for (int off = 32; off; off >>= 1) s += __shfl_xor(s, off);
        if (lane == 0) { wm[w] = m; wsum[w] = s; }
        #pragma unroll
        for (int d = 0; d < 24; ++d) {
            float rv = r_l[d] * fac;
            #pragma unroll
            for (int off = 32; off; off >>= 1) rv += __shfl_xor(rv, off);
            if (lane == d) wr[w][d] = rv;   // compile-time d
        }
        __syncthreads();
        // cross-wave merge (t<24)
        if (t < 24) {
            float mg = fmaxf(fmaxf(wm[0], wm[1]), fmaxf(wm[2], wm[3]));
            float mgs = (mg == -INFINITY) ? 0.0f : mg;
            float den = 0.0f, acc = 0.0f;
            #pragma unroll
            for (int ww = 0; ww < 4; ++ww) {
                float fw = (wm[ww] == -INFINITY) ? 0.0f : expf(wm[ww] - mgs);
                den = fmaf(wsum[ww], fw, den);
                acc = fmaf(wr[ww][t], fw, acc);
            }
            qs[24 + t] = acc / fmaxf(den, 1e-16f);
        }
        __syncthreads();
    }

    // ---- head: out = relu(q_star@w_fc2+b2)@w_fc3+b3 ----
    if (t < 8) {
        float a = b_fc2[t];
        #pragma unroll
        for (int j = 0; j < 48; ++j) a = fmaf(qs[j], w_fc2[j * 8 + t], a);
        zl[t] = fmaxf(a, 0.0f);
    }
    __syncthreads();
    if (t < 2) {
        float a = b_fc3[t];
        #pragma unroll
        for (int k = 0; k < 8; ++k) a = fmaf(zl[k], w_fc3[k * 2 + t], a);
        out[(size_t)g * 2 + t] = a;
    }
}

extern "C" void kernel_launch(void* const* d_in, const int* in_sizes, int n_in,
                              void* d_out, int out_size, void* d_ws, size_t ws_size,
                              hipStream_t stream) {
    const float* x      = (const float*)d_in[0];
    const float* ea     = (const float*)d_in[1];
    const float* w_e1   = (const float*)d_in[2];
    const float* b_e1   = (const float*)d_in[3];
    const float* w_e2   = (const float*)d_in[4];
    const float* b_e2   = (const float*)d_in[5];
    const float* root   = (const float*)d_in[6];
    const float* bias_c = (const float*)d_in[7];
    const float* w_ih   = (const float*)d_in[8];
    const float* w_hh   = (const float*)d_in[9];
    const float* b_ih   = (const float*)d_in[10];
    const float* b_hh   = (const float*)d_in[11];
    const float* w_fc2  = (const float*)d_in[12];
    const float* b_fc2  = (const float*)d_in[13];
    const float* w_fc3  = (const float*)d_in[14];
    const float* b_fc3  = (const float*)d_in[15];
    const int*   eidx   = (const int*)d_in[16];
    const int*   batch  = (const int*)d_in[17];
    const int* esrc = eidx;
    const int* edst = eidx + N_EDGES;
    float* out = (float*)d_out;

    // workspace layout (bytes)
    char* ws = (char*)d_ws;
    float* agg   = (float*)(ws);                  // 4,800,000
    int*   deg   = (int*)  (ws + 4800000);        //   200,000
    float* x1    = (float*)(ws + 5789824);        // 4,800,000
    float* x2    = (float*)(ws + 10589824);       // 4,800,000
    f16*   Bz    = (f16*)  (ws + 15389824);       //   198,656 swizzled f16 w2+b2
    float* rootT = (float*)(ws + 15588480);       //     2,304 transposed root
    int*   offs  = (int*)  (ws + 15590784);       //     4,100 graph offsets [1025]

    // zero: agg + deg
    hipMemsetAsync(ws, 0, 5000000, stream);

    // deg + Bz + rootT + offs in one dispatch
    prep_kernel<<<1369, 256, 0, stream>>>(edst, deg, w_e2, b_e2, root, batch, Bz, rootT, offs);

    // layer 1 (fused edge-MLP + message + scatter; no W materialization)
    conv_kernel<<<(N_EDGES + 127) / 128, 256, 0, stream>>>(x, ea, w_e1, b_e1, Bz, esrc, edst, agg);
    combine_kernel<<<(N_NODES * 4 + 255) / 256, 256, 0, stream>>>(x, agg, deg, rootT, bias_c, x1, 1, 1);

    // layer 2 (agg was re-zeroed by combine 1)
    conv_kernel<<<(N_EDGES + 127) / 128, 256, 0, stream>>>(x1, ea, w_e1, b_e1, Bz, esrc, edst, agg);
    combine_kernel<<<(N_NODES * 4 + 255) / 256, 256, 0, stream>>>(x1, agg, deg, rootT, bias_c, x2, 0, 0);

    // fused Set2Set (3 iterations) + head: one block (4 waves) per graph
    s2s_kernel<<<N_GRAPHS, 256, 0, stream>>>(x2, offs, w_ih, w_hh, b_ih, b_hh,
                                             w_fc2, b_fc2, w_fc3, b_fc3, out);
}